// Round 12
// baseline (1045.536 us; speedup 1.0000x reference)
//
#include <hip/hip_runtime.h>

typedef unsigned short u16;
typedef __attribute__((ext_vector_type(4))) float f32x4;
typedef __attribute__((ext_vector_type(8))) short s16x8;

constexpr int N = 16, L = 2048, C = 1024;
constexpr int NL = N * L;

__device__ __forceinline__ u16 f2bf(float v) {
  unsigned u = __float_as_uint(v);
  return (u16)((u + 0x7FFFu + ((u >> 16) & 1u)) >> 16);
}
__device__ __forceinline__ float bf2f(u16 h) { return __uint_as_float(((unsigned)h) << 16); }
__device__ __forceinline__ void split1(float v, u16 &h, u16 &l) {
  h = f2bf(v);
  l = f2bf(v - bf2f(h));
}

__device__ __forceinline__ void gload16(const void* g, const void* l) {
  __builtin_amdgcn_global_load_lds((const __attribute__((address_space(1))) void*)g,
                                   (__attribute__((address_space(3))) void*)l, 16, 0, 0);
}

// ------------------------------------------------- fused x preprocessing
__global__ __launch_bounds__(256) void xprep(const float* __restrict__ x,
                                             u16* __restrict__ xh,
                                             u16* __restrict__ xl,
                                             u16* __restrict__ xT) {
  __shared__ u16 tile[64 * 68];
  const int n = blockIdx.z;
  const int l0 = blockIdx.x * 64;
  const int c0 = blockIdx.y * 64;
  const int t = threadIdx.x;
  const int cg = t & 15, r = t >> 4;
#pragma unroll
  for (int i = 0; i < 4; ++i) {
    int rr = r + i * 16;
    size_t idx = ((size_t)n * L + l0 + rr) * C + c0 + cg * 4;
    float4 v = *(const float4*)&x[idx];
    ushort4 h, l;
    split1(v.x, h.x, l.x); split1(v.y, h.y, l.y);
    split1(v.z, h.z, l.z); split1(v.w, h.w, l.w);
    *(ushort4*)&xh[idx] = h;
    *(ushort4*)&xl[idx] = l;
    *(ushort4*)&tile[rr * 68 + cg * 4] = h;
  }
  __syncthreads();
  const int l4 = (t & 15) * 4;
#pragma unroll
  for (int i = 0; i < 4; ++i) {
    int cc = (t >> 4) + i * 16;
    ushort4 o;
    o.x = tile[(l4 + 0) * 68 + cc];
    o.y = tile[(l4 + 1) * 68 + cc];
    o.z = tile[(l4 + 2) * 68 + cc];
    o.w = tile[(l4 + 3) * 68 + cc];
    *(ushort4*)&xT[((size_t)n * C + c0 + cc) * L + l0 + l4] = o;
  }
}

// --------------------------------------- W transpose + hi/lo split
__global__ __launch_bounds__(256) void transpose_w(
    const float* __restrict__ Wq, const float* __restrict__ Wk,
    u16* __restrict__ WqTh, u16* __restrict__ WqTl,
    u16* __restrict__ WkTh, u16* __restrict__ WkTl) {
  __shared__ u16 th[64 * 68], tl[64 * 68];
  const float* W = blockIdx.z ? Wk : Wq;
  u16* Th = blockIdx.z ? WkTh : WqTh;
  u16* Tl = blockIdx.z ? WkTl : WqTl;
  const int a0 = blockIdx.x * 64, c0 = blockIdx.y * 64;
  const int t = threadIdx.x, cg = t & 15, r = t >> 4;
#pragma unroll
  for (int i = 0; i < 4; ++i) {
    int rr = r + i * 16;
    float4 v = *(const float4*)&W[(size_t)(a0 + rr) * C + c0 + cg * 4];
    ushort4 h, l;
    split1(v.x, h.x, l.x); split1(v.y, h.y, l.y);
    split1(v.z, h.z, l.z); split1(v.w, h.w, l.w);
    *(ushort4*)&th[rr * 68 + cg * 4] = h;
    *(ushort4*)&tl[rr * 68 + cg * 4] = l;
  }
  __syncthreads();
  const int a4 = (t & 15) * 4;
#pragma unroll
  for (int i = 0; i < 4; ++i) {
    int cc = (t >> 4) + i * 16;
    ushort4 oh, ol;
    oh.x = th[(a4 + 0) * 68 + cc]; ol.x = tl[(a4 + 0) * 68 + cc];
    oh.y = th[(a4 + 1) * 68 + cc]; ol.y = tl[(a4 + 1) * 68 + cc];
    oh.z = th[(a4 + 2) * 68 + cc]; ol.z = tl[(a4 + 2) * 68 + cc];
    oh.w = th[(a4 + 3) * 68 + cc]; ol.w = tl[(a4 + 3) * 68 + cc];
    *(ushort4*)&Th[(size_t)(c0 + cc) * C + a0 + a4] = oh;
    *(ushort4*)&Tl[(size_t)(c0 + cc) * C + a0 + a4] = ol;
  }
}

// ----------------------------------- MT = Wq^T * Wk (3-pass, 64x64 tiles)
__global__ __launch_bounds__(256) void g_m(
    const u16* __restrict__ Ah, const u16* __restrict__ Al,
    const u16* __restrict__ Bh, const u16* __restrict__ Bl,
    u16* __restrict__ Mh, u16* __restrict__ Ml) {
  __shared__ u16 sAh[64 * 64], sAl[64 * 64], sBh[64 * 64], sBl[64 * 64];
  const int i0 = blockIdx.y * 64, j0 = blockIdx.x * 64;
  const int t = threadIdx.x, lane = t & 63, w = t >> 6;
  const int wr = w >> 1, wc = w & 1;
  const int lr = lane & 15, lk = lane >> 4;
  const int g8 = t & 7, rb = t >> 3;
  f32x4 acc[2][2] = {};
  for (int kk = 0; kk < C; kk += 64) {
    __syncthreads();
#pragma unroll
    for (int i = 0; i < 2; ++i) {
      int r = rb + i * 32;
      *(uint4*)&sAh[r * 64 + g8 * 8] = *(const uint4*)&Ah[(size_t)(i0 + r) * C + kk + g8 * 8];
      *(uint4*)&sAl[r * 64 + g8 * 8] = *(const uint4*)&Al[(size_t)(i0 + r) * C + kk + g8 * 8];
      *(uint4*)&sBh[r * 64 + g8 * 8] = *(const uint4*)&Bh[(size_t)(j0 + r) * C + kk + g8 * 8];
      *(uint4*)&sBl[r * 64 + g8 * 8] = *(const uint4*)&Bl[(size_t)(j0 + r) * C + kk + g8 * 8];
    }
    __syncthreads();
#pragma unroll
    for (int ks = 0; ks < 2; ++ks)
#pragma unroll
      for (int mi = 0; mi < 2; ++mi) {
        s16x8 ah = *(const s16x8*)&sAh[(wr * 32 + mi * 16 + lr) * 64 + ks * 32 + lk * 8];
        s16x8 al = *(const s16x8*)&sAl[(wr * 32 + mi * 16 + lr) * 64 + ks * 32 + lk * 8];
#pragma unroll
        for (int ni = 0; ni < 2; ++ni) {
          s16x8 bh = *(const s16x8*)&sBh[(wc * 32 + ni * 16 + lr) * 64 + ks * 32 + lk * 8];
          s16x8 bl = *(const s16x8*)&sBl[(wc * 32 + ni * 16 + lr) * 64 + ks * 32 + lk * 8];
          acc[mi][ni] = __builtin_amdgcn_mfma_f32_16x16x32_bf16(ah, bh, acc[mi][ni], 0, 0, 0);
          acc[mi][ni] = __builtin_amdgcn_mfma_f32_16x16x32_bf16(ah, bl, acc[mi][ni], 0, 0, 0);
          acc[mi][ni] = __builtin_amdgcn_mfma_f32_16x16x32_bf16(al, bh, acc[mi][ni], 0, 0, 0);
        }
      }
  }
#pragma unroll
  for (int mi = 0; mi < 2; ++mi)
#pragma unroll
    for (int ni = 0; ni < 2; ++ni)
#pragma unroll
      for (int j = 0; j < 4; ++j) {
        int rr = i0 + wr * 32 + mi * 16 + lk * 4 + j;
        int cc = j0 + wc * 32 + ni * 16 + lr;
        u16 h, l;
        split1(acc[mi][ni][j], h, l);
        Mh[(size_t)rr * C + cc] = h;
        Ml[(size_t)rr * C + cc] = l;
      }
}

// --------------- 8-phase 256x256 GEMM + wave-group read-priority stagger
// MODE 0 (P):      P[nl][c'] = sum_c x[nl][c]*MT[c'][c]; K'=3C; out bf16 hi/lo.
// MODE 1 (SCORES): S[l][m] = sum_c P[l][c]*x[m][c]; K'=3C; out bf16 e-values
//                  exp(S - blockmax) + block stats (bm, sum_e) per (col, by).
// Stagger: waves w<4 (one per SIMD) get issue priority during the per-phase
// ds_read batch -> their reads queue first in the LDS pipe -> they release
// from lgkm waits earlier -> their MFMA burst overlaps group-B's read drain.
#define PH_OPEN() asm volatile("s_barrier" ::: "memory")
#define PH_CLOSE() asm volatile("s_barrier" ::: "memory")
#define VMCNT4() asm volatile("s_waitcnt vmcnt(4)" ::: "memory")
#define VMCNT0() asm volatile("s_waitcnt vmcnt(0)" ::: "memory")
#define RDP_ON()  do { if (w < 4) __builtin_amdgcn_s_setprio(1); } while (0)
#define RDP_OFF() do { if (w < 4) __builtin_amdgcn_s_setprio(0); } while (0)

#define MFMAQ(MH, NH, AV, BV)                                              \
  do {                                                                     \
    __builtin_amdgcn_s_setprio(1);                                         \
    _Pragma("unroll") for (int ks = 0; ks < 2; ++ks)                       \
        _Pragma("unroll") for (int mi = 0; mi < 4; ++mi)                   \
        _Pragma("unroll") for (int ni = 0; ni < 2; ++ni)                   \
            acc[MH * 4 + mi][NH * 2 + ni] =                                \
        __builtin_amdgcn_mfma_f32_16x16x32_bf16(                           \
            AV[mi * 2 + ks], BV[ni * 2 + ks], acc[MH * 4 + mi][NH * 2 + ni], 0, 0, 0); \
    __builtin_amdgcn_s_setprio(0);                                         \
  } while (0)

template <int MODE>
__device__ __forceinline__ void gemm8_body(
    const u16* __restrict__ A0, const u16* __restrict__ A1,
    const u16* __restrict__ B0, const u16* __restrict__ B1,
    u16* __restrict__ Oh, u16* __restrict__ Ol, u16* __restrict__ E,
    float2* __restrict__ PS, int n0) {
  constexpr int NT = 48;  // K-tiles of 64 (3 segments x 16)
  constexpr int NI = NT / 2;
  constexpr int SA = 2048, SB = 2048;
  constexpr int GXL = (MODE == 0) ? 2 : 3;
  __shared__ u16 lds[65536];

  const int nwg = gridDim.x * gridDim.y * gridDim.z;
  int lin = ((int)blockIdx.z * gridDim.y + blockIdx.y) * gridDim.x + blockIdx.x;
  int swz = (lin & 7) * (nwg >> 3) + (lin >> 3);
  const int bx = swz & ((1 << GXL) - 1);
  int rem = swz >> GXL;
  const int by = (MODE == 0) ? rem : (rem & 7);
  const int bz = (MODE == 0) ? 0 : (rem >> 3);

  const int zn = bz;
  const int row0 = by * 256;
  const int col0 = bx * 256;
  const char *aB0, *aB1, *bB0, *bB1;
  if constexpr (MODE == 0) {
    aB0 = (const char*)(A0 + (size_t)row0 * C);   // xh rows
    aB1 = (const char*)(A1 + (size_t)row0 * C);   // xl rows
    bB0 = (const char*)(B0 + (size_t)col0 * C);   // MTh rows
    bB1 = (const char*)(B1 + (size_t)col0 * C);   // MTl rows
  } else {
    const int n = n0 + zn;
    aB0 = (const char*)(A0 + ((size_t)n * L + row0) * C);  // Ph
    aB1 = (const char*)(A1 + ((size_t)n * L + row0) * C);  // Pl
    bB0 = (const char*)(B0 + ((size_t)n * L + col0) * C);  // xh
    bB1 = (const char*)(B1 + ((size_t)n * L + col0) * C);  // xl
  }

  const int t = threadIdx.x;
  const int lane = t & 63, w = t >> 6;
  const int wr = w >> 2, wc = w & 3;
  const int lr = lane & 15, lk = lane >> 4;

  const int rp0 = w * 8 + (lane >> 3);
  const int rp1 = 64 + rp0;
  const int g = (lane & 7) ^ ((lane >> 3) & 7);
  const int dO0 = w * 512 + (lane >> 3) * 64 + (lane & 7) * 8;
  const int dO1 = 4096 + dO0;
  const int sA0_0 = ((rp0 & 63) | ((rp0 >> 6) << 7)) * SA + g * 16;
  const int sA0_1 = ((rp1 & 63) | ((rp1 >> 6) << 7)) * SA + g * 16;
  const int sA1_0 = (((rp0 & 63) | 64) | ((rp0 >> 6) << 7)) * SA + g * 16;
  const int sA1_1 = (((rp1 & 63) | 64) | ((rp1 >> 6) << 7)) * SA + g * 16;
  const int sB0_0 = ((rp0 & 31) | ((rp0 >> 5) << 6)) * SB + g * 16;
  const int sB0_1 = ((rp1 & 31) | ((rp1 >> 5) << 6)) * SB + g * 16;
  const int sB1_0 = (((rp0 & 31) | 32) | ((rp0 >> 5) << 6)) * SB + g * 16;
  const int sB1_1 = (((rp1 & 31) | 32) | ((rp1 >> 5) << 6)) * SB + g * 16;

  auto stage = [&](int kt, int so0, int so1, int rbase, bool isB) {
    const int seg = kt >> 4;
    const char* p = isB ? (seg == 1 ? bB1 : bB0) : (seg == 2 ? aB1 : aB0);
    const int kOff = (kt & 15) * 128;
    u16* dst = &lds[(kt & 1) * 32768 + rbase];
    gload16(p + kOff + so0, dst + dO0);
    gload16(p + kOff + so1, dst + dO1);
  };

  auto dsA = [&](int d, int mh, s16x8* av) {
#pragma unroll
    for (int mi = 0; mi < 4; ++mi)
#pragma unroll
      for (int ks = 0; ks < 2; ++ks)
        av[mi * 2 + ks] = *(const s16x8*)&lds[d * 32768 + mh * 8192 +
                                              (wr * 64 + mi * 16 + lr) * 64 +
                                              (((ks * 4 + lk) ^ (lr & 7)) * 8)];
  };
  auto dsB = [&](int d, int nh, s16x8* bv) {
#pragma unroll
    for (int ni = 0; ni < 2; ++ni)
#pragma unroll
      for (int ks = 0; ks < 2; ++ks)
        bv[ni * 2 + ks] = *(const s16x8*)&lds[d * 32768 + 16384 + nh * 8192 +
                                              (wc * 32 + ni * 16 + lr) * 64 +
                                              (((ks * 4 + lk) ^ (lr & 7)) * 8)];
  };

  f32x4 acc[8][4] = {};
  s16x8 av[8], b0v[4], b1v[4];

  // prologue: t0 fully + t1.{A0,B0}; b0v read AFTER the certifying barrier.
  stage(0, sA0_0, sA0_1, 0, false);
  stage(0, sB0_0, sB0_1, 16384, true);
  stage(0, sA1_0, sA1_1, 8192, false);
  stage(0, sB1_0, sB1_1, 24576, true);
  stage(1, sA0_0, sA0_1, 0, false);
  stage(1, sB0_0, sB0_1, 16384, true);
  VMCNT4();
  PH_CLOSE();
  dsB(0, 0, b0v);

  for (int i = 0; i < NI; ++i) {
    const int t1 = 2 * i + 1, t2 = 2 * i + 2, t3 = 2 * i + 3;
    // ph1: Q(0,0) d0  [8 reads, group-A priority]
    RDP_ON();
    dsA(0, 0, av);
    RDP_OFF();
    stage(t1, sA1_0, sA1_1, 8192, false);
    PH_OPEN();
    MFMAQ(0, 0, av, b0v);
    PH_CLOSE();
    // ph2: Q(0,1) d0  [4 reads]
    RDP_ON();
    dsB(0, 1, b1v);
    RDP_OFF();
    stage(t1, sB1_0, sB1_1, 24576, true);
    PH_OPEN();
    MFMAQ(0, 1, av, b1v);
    PH_CLOSE();
    // ph3: Q(1,0) d0  [8 reads]
    RDP_ON();
    dsA(0, 1, av);
    RDP_OFF();
    if (t2 < NT) stage(t2, sA0_0, sA0_1, 0, false);
    PH_OPEN();
    MFMAQ(1, 0, av, b0v);
    PH_CLOSE();
    // ph4: Q(1,1) d0; d1 certified after this barrier -> in-window b0v read.
    if (t2 < NT) {
      stage(t2, sB0_0, sB0_1, 16384, true);
      VMCNT4();
    } else {
      VMCNT0();
    }
    PH_OPEN();
    dsB(1, 0, b0v);
    MFMAQ(1, 1, av, b1v);
    PH_CLOSE();
    // ph5: Q(0,0) d1  [8 reads]
    RDP_ON();
    dsA(1, 0, av);
    RDP_OFF();
    if (t2 < NT) stage(t2, sA1_0, sA1_1, 8192, false);
    PH_OPEN();
    MFMAQ(0, 0, av, b0v);
    PH_CLOSE();
    // ph6: Q(0,1) d1  [4 reads]
    RDP_ON();
    dsB(1, 1, b1v);
    RDP_OFF();
    if (t2 < NT) stage(t2, sB1_0, sB1_1, 24576, true);
    PH_OPEN();
    MFMAQ(0, 1, av, b1v);
    PH_CLOSE();
    // ph7: Q(1,0) d1  [8 reads]
    RDP_ON();
    dsA(1, 1, av);
    RDP_OFF();
    if (t3 < NT) stage(t3, sA0_0, sA0_1, 0, false);
    PH_OPEN();
    MFMAQ(1, 0, av, b0v);
    PH_CLOSE();
    // ph8: Q(1,1) d1; next d0 certified after this barrier -> in-window read.
    if (t3 < NT) {
      stage(t3, sB0_0, sB0_1, 16384, true);
      VMCNT4();
    } else {
      VMCNT0();
    }
    PH_OPEN();
    dsB(0, 0, b0v);  // garbage on final iteration, unused
    MFMAQ(1, 1, av, b1v);
    PH_CLOSE();
  }
  asm volatile("s_waitcnt lgkmcnt(0)" ::: "memory");

  // ------------------------------------------------------------ epilogue
  if constexpr (MODE == 0) {
#pragma unroll
    for (int mg = 0; mg < 8; ++mg)
#pragma unroll
      for (int ng = 0; ng < 4; ++ng) {
        const int r = row0 + wr * 128 + (mg >> 2) * 64 + (mg & 3) * 16 + lk * 4;
        const int c = col0 + wc * 64 + (ng >> 1) * 32 + (ng & 1) * 16 + lr;
        const f32x4 v = acc[mg][ng];
#pragma unroll
        for (int j = 0; j < 4; ++j) {
          u16 h, l;
          split1(v[j], h, l);
          Oh[(size_t)(r + j) * C + c] = h;
          Ol[(size_t)(r + j) * C + c] = l;
        }
      }
  } else {
    // e-value epilogue: block col-max (LDS reduce), then e = exp(S-bm) bf16,
    // per-thread sums -> block stats PS = (bm, sum_e) per (col, by).
    const int gn = n0 + zn;
    float* sm_ = (float*)lds;          // [256 cols][stride 9] maxes
    float* ss_ = (float*)lds + 2304;   // [256 cols][stride 9] sums
#pragma unroll
    for (int ng = 0; ng < 4; ++ng) {
      float mx = -3.0e38f;
#pragma unroll
      for (int mg = 0; mg < 8; ++mg)
#pragma unroll
        for (int j = 0; j < 4; ++j) mx = fmaxf(mx, acc[mg][ng][j]);
      const int cl = wc * 64 + (ng >> 1) * 32 + (ng & 1) * 16 + lr;
      sm_[cl * 9 + wr * 4 + lk] = mx;
    }
    __syncthreads();
#pragma unroll
    for (int ng = 0; ng < 4; ++ng) {
      const int cl = wc * 64 + (ng >> 1) * 32 + (ng & 1) * 16 + lr;
      float bm = -3.0e38f;
#pragma unroll
      for (int s = 0; s < 8; ++s) bm = fmaxf(bm, sm_[cl * 9 + s]);
      float sum = 0.f;
#pragma unroll
      for (int mg = 0; mg < 8; ++mg) {
        const int r = row0 + wr * 128 + (mg >> 2) * 64 + (mg & 3) * 16 + lk * 4;
#pragma unroll
        for (int j = 0; j < 4; ++j) {
          float ev = __expf(acc[mg][ng][j] - bm);
          sum += ev;
          E[((size_t)zn * L + r + j) * L + col0 + cl] = f2bf(ev);
        }
      }
      ss_[cl * 9 + wr * 4 + lk] = sum;
    }
    __syncthreads();
    if (t < 256) {
      float bm = -3.0e38f, sum = 0.f;
#pragma unroll
      for (int s = 0; s < 8; ++s) {
        bm = fmaxf(bm, sm_[t * 9 + s]);
        sum += ss_[t * 9 + s];
      }
      PS[((size_t)gn * L + col0 + t) * 8 + by] = make_float2(bm, sum);
    }
  }
}

__global__ __launch_bounds__(512, 2) void g_p(
    const u16* A0, const u16* A1, const u16* B0, const u16* B1,
    u16* Oh, u16* Ol) {
  gemm8_body<0>(A0, A1, B0, B1, Oh, Ol, nullptr, nullptr, 0);
}
__global__ __launch_bounds__(512, 2) void g_sc(
    const u16* A0, const u16* A1, const u16* B0, const u16* B1,
    u16* E, float2* PS, int n0) {
  gemm8_body<1>(A0, A1, B0, B1, nullptr, nullptr, E, PS, n0);
}

// ---------------------- stats merge -> per-(segment, col) rescale factors
// fac[n][s][m] = exp(bm[s][m] - gm[m]) / sum_total[m]
__global__ __launch_bounds__(256) void stats_merge(const float2* __restrict__ pstats,
                                                   float* __restrict__ fac,
                                                   int n0) {
  const int gn = n0 + blockIdx.z;
  const int m = blockIdx.x * 256 + threadIdx.x;
  const float2* p = &pstats[((size_t)gn * L + m) * 8];
  float2 pv[8];
  float gm = -3.0e38f;
#pragma unroll
  for (int j = 0; j < 8; ++j) { pv[j] = p[j]; gm = fmaxf(gm, pv[j].x); }
  float gs = 0.f;
#pragma unroll
  for (int j = 0; j < 8; ++j) gs += pv[j].y * __expf(pv[j].x - gm);
  const float inv = 1.f / gs;
#pragma unroll
  for (int s = 0; s < 8; ++s)
    fac[((size_t)gn * 8 + s) * L + m] = __expf(pv[s].x - gm) * inv;
}

// ------------------------------- out GEMM (bf16 e * fac staging, 128x256)
__global__ __launch_bounds__(512, 4) void gemm_out_k(
    const u16* __restrict__ e, const float* __restrict__ fac,
    const u16* __restrict__ xT, float* __restrict__ out, int n0) {
  __shared__ u16 lA[128 * 64];
  __shared__ u16 lB[256 * 64];
  const int nwg = gridDim.x * gridDim.y * gridDim.z;
  int lin = ((int)blockIdx.z * gridDim.y + blockIdx.y) * gridDim.x + blockIdx.x;
  int swz = (lin & 7) * (nwg >> 3) + (lin >> 3);
  const int bx = swz & 3, by = (swz >> 2) & 15, bz = swz >> 6;
  const int zn = bz, gn = n0 + zn;
  const int row0 = by * 128, col0 = bx * 256;
  const u16* Ee = e + (size_t)zn * L * L + (size_t)row0 * L;
  const float* fr = fac + ((size_t)gn * 8 + (by >> 1)) * L;
  const char* bB = (const char*)(xT + ((size_t)gn * C + col0) * L);
  float* O = out + ((size_t)gn * L + row0) * C + col0;

  const int t = threadIdx.x;
  const int lane = t & 63, w = t >> 6;
  const int wr = w >> 2, wc = w & 3;
  const int lr = lane & 15, lk = lane >> 4;
  const int c4 = t & 15, rb4 = t >> 4;
  const int gB = (t & 7) ^ ((t >> 3) & 7);
  const int Rb = t >> 3;

  auto aoff = [&](int r, int k) { return r * 64 + (((k >> 3) ^ (r & 7)) << 3) + (k & 7); };

  ushort4 ev4[4];
  float4 fv;
  auto loadA = [&](int kt) {
#pragma unroll
    for (int i = 0; i < 4; ++i)
      ev4[i] = *(const ushort4*)&Ee[(size_t)(rb4 + i * 32) * L + kt * 64 + c4 * 4];
    fv = *(const float4*)&fr[kt * 64 + c4 * 4];
  };

  f32x4 acc[4][4] = {};
  loadA(0);
  for (int kt = 0; kt < 32; ++kt) {
    ushort4 pk[4];
#pragma unroll
    for (int i = 0; i < 4; ++i) {
      pk[i].x = f2bf(bf2f(ev4[i].x) * fv.x);
      pk[i].y = f2bf(bf2f(ev4[i].y) * fv.y);
      pk[i].z = f2bf(bf2f(ev4[i].z) * fv.z);
      pk[i].w = f2bf(bf2f(ev4[i].w) * fv.w);
    }
    __syncthreads();
#pragma unroll
    for (int i = 0; i < 4; ++i)
      *(ushort4*)&lA[aoff(rb4 + i * 32, c4 * 4)] = pk[i];
#pragma unroll
    for (int i = 0; i < 4; ++i)
      gload16(bB + (size_t)(Rb + i * 64) * (L * 2) + kt * 128 + gB * 16,
              &lB[(Rb + i * 64) * 64 + (t & 7) * 8]);
    if (kt < 31) {
      loadA(kt + 1);  // 5 vmem after the 4 B-gloads
      asm volatile("s_waitcnt vmcnt(5) lgkmcnt(0)" ::: "memory");
    } else {
      asm volatile("s_waitcnt vmcnt(0) lgkmcnt(0)" ::: "memory");
    }
    __syncthreads();
#pragma unroll
    for (int ks = 0; ks < 2; ++ks) {
      s16x8 bf[4];
#pragma unroll
      for (int ni = 0; ni < 4; ++ni)
        bf[ni] = *(const s16x8*)&lB[aoff(wc * 64 + ni * 16 + lr, ks * 32 + lk * 8)];
      __builtin_amdgcn_s_setprio(1);
#pragma unroll
      for (int mi = 0; mi < 4; ++mi) {
        s16x8 af = *(const s16x8*)&lA[aoff(wr * 64 + mi * 16 + lr, ks * 32 + lk * 8)];
#pragma unroll
        for (int ni = 0; ni < 4; ++ni)
          acc[mi][ni] = __builtin_amdgcn_mfma_f32_16x16x32_bf16(af, bf[ni], acc[mi][ni], 0, 0, 0);
      }
      __builtin_amdgcn_s_setprio(0);
    }
  }
#pragma unroll
  for (int mi = 0; mi < 4; ++mi)
#pragma unroll
    for (int ni = 0; ni < 4; ++ni)
#pragma unroll
      for (int j = 0; j < 4; ++j)
        O[(size_t)(wr * 64 + mi * 16 + lk * 4 + j) * C + wc * 64 + ni * 16 + lr] =
            acc[mi][ni][j];
}

// ----------------------------------------------------------------- launch
extern "C" void kernel_launch(void* const* d_in, const int* in_sizes, int n_in,
                              void* d_out, int out_size, void* d_ws, size_t ws_size,
                              hipStream_t stream) {
  const float* x = (const float*)d_in[0];
  const float* Wq = (const float*)d_in[1];
  const float* Wk = (const float*)d_in[2];
  float* out = (float*)d_out;

  char* ws = (char*)d_ws;
  size_t off = 0;
  auto alloc = [&](size_t bytes) -> void* {
    void* p = ws + off;
    off = (off + bytes + 255) & ~(size_t)255;
    return p;
  };
  u16* MTh = (u16*)alloc((size_t)C * C * 2);
  u16* MTl = (u16*)alloc((size_t)C * C * 2);
  u16* WqTh = (u16*)alloc((size_t)C * C * 2);
  u16* WqTl = (u16*)alloc((size_t)C * C * 2);
  u16* WkTh = (u16*)alloc((size_t)C * C * 2);
  u16* WkTl = (u16*)alloc((size_t)C * C * 2);
  u16* xh = (u16*)alloc((size_t)NL * C * 2);
  u16* xl = (u16*)alloc((size_t)NL * C * 2);
  u16* xT = (u16*)alloc((size_t)N * C * L * 2);
  u16* Ph = (u16*)alloc((size_t)NL * C * 2);
  u16* Pl = (u16*)alloc((size_t)NL * C * 2);
  float2* pstats = (float2*)alloc((size_t)N * L * 8 * 8);
  float* fac = (float*)alloc((size_t)N * 8 * L * 4);
  const size_t base = off;
  const size_t per_n = (size_t)L * L * 2;  // bf16 e-values
  size_t avail = ws_size > base ? ws_size - base : 0;
  int chunk = (int)(avail / per_n);
  if (chunk < 1) chunk = 1;
  if (chunk > 16) chunk = 16;
  u16* e = (u16*)(ws + base);

  xprep<<<dim3(L / 64, C / 64, N), dim3(256), 0, stream>>>(x, xh, xl, xT);
  transpose_w<<<dim3(16, 16, 2), dim3(256), 0, stream>>>(Wq, Wk, WqTh, WqTl, WkTh, WkTl);
  g_m<<<dim3(16, 16), dim3(256), 0, stream>>>(WqTh, WqTl, WkTh, WkTl, MTh, MTl);
  g_p<<<dim3(4, 128), dim3(512), 0, stream>>>(xh, xl, MTh, MTl, Ph, Pl);
  for (int n0 = 0; n0 < N; n0 += chunk) {
    int cn = (N - n0) < chunk ? (N - n0) : chunk;
    g_sc<<<dim3(8, 8, cn), dim3(512), 0, stream>>>(Ph, Pl, xh, xl, e, pstats, n0);
    stats_merge<<<dim3(L / 256, 1, cn), dim3(256), 0, stream>>>(pstats, fac, n0);
    gemm_out_k<<<dim3(4, 16, cn), dim3(512), 0, stream>>>(e, fac, xT, out, n0);
  }
}

// Round 13
// 660.330 us; speedup vs baseline: 1.5834x; 1.5834x over previous
//
#include <hip/hip_runtime.h>

typedef unsigned short u16;
typedef __attribute__((ext_vector_type(4))) float f32x4;
typedef __attribute__((ext_vector_type(8))) short s16x8;
typedef _Float16 f16x8 __attribute__((ext_vector_type(8)));

constexpr int N = 16, L = 2048, C = 1024;
constexpr int NL = N * L;

__device__ __forceinline__ u16 f2bf(float v) {
  unsigned u = __float_as_uint(v);
  return (u16)((u + 0x7FFFu + ((u >> 16) & 1u)) >> 16);
}
__device__ __forceinline__ u16 f2h(float v) {
  _Float16 h = (_Float16)v;
  return __builtin_bit_cast(u16, h);
}
// fp16 hi/lo split: v = h + l with |residual| <= 2^-22 * |v|
__device__ __forceinline__ void split16(float v, u16 &h, u16 &l) {
  _Float16 hh = (_Float16)v;
  _Float16 ll = (_Float16)(v - (float)hh);
  h = __builtin_bit_cast(u16, hh);
  l = __builtin_bit_cast(u16, ll);
}
__device__ __forceinline__ float bf2f(u16 h) { return __uint_as_float(((unsigned)h) << 16); }

__device__ __forceinline__ void gload16(const void* g, const void* l) {
  __builtin_amdgcn_global_load_lds((const __attribute__((address_space(1))) void*)g,
                                   (__attribute__((address_space(3))) void*)l, 16, 0, 0);
}

// ------------------------------------------------- fused x preprocessing
// x [N][L][C] fp32 -> xh16 (fp16, same layout) + xT [N][C][L] bf16
__global__ __launch_bounds__(256) void xprep(const float* __restrict__ x,
                                             u16* __restrict__ xh,
                                             u16* __restrict__ xT) {
  __shared__ u16 tile[64 * 68];
  const int n = blockIdx.z;
  const int l0 = blockIdx.x * 64;
  const int c0 = blockIdx.y * 64;
  const int t = threadIdx.x;
  const int cg = t & 15, r = t >> 4;
#pragma unroll
  for (int i = 0; i < 4; ++i) {
    int rr = r + i * 16;
    size_t idx = ((size_t)n * L + l0 + rr) * C + c0 + cg * 4;
    float4 v = *(const float4*)&x[idx];
    ushort4 h;
    h.x = f2h(v.x); h.y = f2h(v.y); h.z = f2h(v.z); h.w = f2h(v.w);
    *(ushort4*)&xh[idx] = h;
    ushort4 b;
    b.x = f2bf(v.x); b.y = f2bf(v.y); b.z = f2bf(v.z); b.w = f2bf(v.w);
    *(ushort4*)&tile[rr * 68 + cg * 4] = b;
  }
  __syncthreads();
  const int l4 = (t & 15) * 4;
#pragma unroll
  for (int i = 0; i < 4; ++i) {
    int cc = (t >> 4) + i * 16;
    ushort4 o;
    o.x = tile[(l4 + 0) * 68 + cc];
    o.y = tile[(l4 + 1) * 68 + cc];
    o.z = tile[(l4 + 2) * 68 + cc];
    o.w = tile[(l4 + 3) * 68 + cc];
    *(ushort4*)&xT[((size_t)n * C + c0 + cc) * L + l0 + l4] = o;
  }
}

// --------------------------------------- W transpose + bf16 hi/lo split
__global__ __launch_bounds__(256) void transpose_w(
    const float* __restrict__ Wq, const float* __restrict__ Wk,
    u16* __restrict__ WqTh, u16* __restrict__ WqTl,
    u16* __restrict__ WkTh, u16* __restrict__ WkTl) {
  __shared__ u16 th[64 * 68], tl[64 * 68];
  const float* W = blockIdx.z ? Wk : Wq;
  u16* Th = blockIdx.z ? WkTh : WqTh;
  u16* Tl = blockIdx.z ? WkTl : WqTl;
  const int a0 = blockIdx.x * 64, c0 = blockIdx.y * 64;
  const int t = threadIdx.x, cg = t & 15, r = t >> 4;
#pragma unroll
  for (int i = 0; i < 4; ++i) {
    int rr = r + i * 16;
    float4 v = *(const float4*)&W[(size_t)(a0 + rr) * C + c0 + cg * 4];
    ushort4 h, l;
    // bf16 hi/lo (used only inside tiny g_m 3-pass)
    h.x = f2bf(v.x); l.x = f2bf(v.x - bf2f(h.x));
    h.y = f2bf(v.y); l.y = f2bf(v.y - bf2f(h.y));
    h.z = f2bf(v.z); l.z = f2bf(v.z - bf2f(h.z));
    h.w = f2bf(v.w); l.w = f2bf(v.w - bf2f(h.w));
    *(ushort4*)&th[rr * 68 + cg * 4] = h;
    *(ushort4*)&tl[rr * 68 + cg * 4] = l;
  }
  __syncthreads();
  const int a4 = (t & 15) * 4;
#pragma unroll
  for (int i = 0; i < 4; ++i) {
    int cc = (t >> 4) + i * 16;
    ushort4 oh, ol;
    oh.x = th[(a4 + 0) * 68 + cc]; ol.x = tl[(a4 + 0) * 68 + cc];
    oh.y = th[(a4 + 1) * 68 + cc]; ol.y = tl[(a4 + 1) * 68 + cc];
    oh.z = th[(a4 + 2) * 68 + cc]; ol.z = tl[(a4 + 2) * 68 + cc];
    oh.w = th[(a4 + 3) * 68 + cc]; ol.w = tl[(a4 + 3) * 68 + cc];
    *(ushort4*)&Th[(size_t)(c0 + cc) * C + a0 + a4] = oh;
    *(ushort4*)&Tl[(size_t)(c0 + cc) * C + a0 + a4] = ol;
  }
}

// ------------------- MT = Wq^T * Wk (bf16 3-pass, tiny) -> fp16 hi/lo out
__global__ __launch_bounds__(256) void g_m(
    const u16* __restrict__ Ah, const u16* __restrict__ Al,
    const u16* __restrict__ Bh, const u16* __restrict__ Bl,
    u16* __restrict__ Mh, u16* __restrict__ Ml) {
  __shared__ u16 sAh[64 * 64], sAl[64 * 64], sBh[64 * 64], sBl[64 * 64];
  const int i0 = blockIdx.y * 64, j0 = blockIdx.x * 64;
  const int t = threadIdx.x, lane = t & 63, w = t >> 6;
  const int wr = w >> 1, wc = w & 1;
  const int lr = lane & 15, lk = lane >> 4;
  const int g8 = t & 7, rb = t >> 3;
  f32x4 acc[2][2] = {};
  for (int kk = 0; kk < C; kk += 64) {
    __syncthreads();
#pragma unroll
    for (int i = 0; i < 2; ++i) {
      int r = rb + i * 32;
      *(uint4*)&sAh[r * 64 + g8 * 8] = *(const uint4*)&Ah[(size_t)(i0 + r) * C + kk + g8 * 8];
      *(uint4*)&sAl[r * 64 + g8 * 8] = *(const uint4*)&Al[(size_t)(i0 + r) * C + kk + g8 * 8];
      *(uint4*)&sBh[r * 64 + g8 * 8] = *(const uint4*)&Bh[(size_t)(j0 + r) * C + kk + g8 * 8];
      *(uint4*)&sBl[r * 64 + g8 * 8] = *(const uint4*)&Bl[(size_t)(j0 + r) * C + kk + g8 * 8];
    }
    __syncthreads();
#pragma unroll
    for (int ks = 0; ks < 2; ++ks)
#pragma unroll
      for (int mi = 0; mi < 2; ++mi) {
        s16x8 ah = *(const s16x8*)&sAh[(wr * 32 + mi * 16 + lr) * 64 + ks * 32 + lk * 8];
        s16x8 al = *(const s16x8*)&sAl[(wr * 32 + mi * 16 + lr) * 64 + ks * 32 + lk * 8];
#pragma unroll
        for (int ni = 0; ni < 2; ++ni) {
          s16x8 bh = *(const s16x8*)&sBh[(wc * 32 + ni * 16 + lr) * 64 + ks * 32 + lk * 8];
          s16x8 bl = *(const s16x8*)&sBl[(wc * 32 + ni * 16 + lr) * 64 + ks * 32 + lk * 8];
          acc[mi][ni] = __builtin_amdgcn_mfma_f32_16x16x32_bf16(ah, bh, acc[mi][ni], 0, 0, 0);
          acc[mi][ni] = __builtin_amdgcn_mfma_f32_16x16x32_bf16(ah, bl, acc[mi][ni], 0, 0, 0);
          acc[mi][ni] = __builtin_amdgcn_mfma_f32_16x16x32_bf16(al, bh, acc[mi][ni], 0, 0, 0);
        }
      }
  }
#pragma unroll
  for (int mi = 0; mi < 2; ++mi)
#pragma unroll
    for (int ni = 0; ni < 2; ++ni)
#pragma unroll
      for (int j = 0; j < 4; ++j) {
        int rr = i0 + wr * 32 + mi * 16 + lk * 4 + j;
        int cc = j0 + wc * 32 + ni * 16 + lr;
        u16 h, l;
        split16(acc[mi][ni][j], h, l);
        Mh[(size_t)rr * C + cc] = h;
        Ml[(size_t)rr * C + cc] = l;
      }
}

// --------------- 8-phase 256x256 fp16 GEMM, 2-pass (K'=2C), R11 schedule
// MODE 0 (P):      P[nl][c'] = sum_c xh16[nl][c]*MT[c'][c]; segments
//                  (xh*MTh, xh*MTl); out fp16 hi/lo.
// MODE 1 (SCORES): S[l][m] = sum_c (Ph+Pl)[l][c]*xh16[m][c]; segments
//                  (Ph*xh, Pl*xh); out bf16 e-values + block stats.
#define PH_OPEN() asm volatile("s_barrier" ::: "memory")
#define PH_CLOSE() asm volatile("s_barrier" ::: "memory")
#define VMCNT4() asm volatile("s_waitcnt vmcnt(4)" ::: "memory")
#define VMCNT0() asm volatile("s_waitcnt vmcnt(0)" ::: "memory")

#define MFMAQ(MH, NH, AV, BV)                                              \
  do {                                                                     \
    __builtin_amdgcn_s_setprio(1);                                         \
    _Pragma("unroll") for (int ks = 0; ks < 2; ++ks)                       \
        _Pragma("unroll") for (int mi = 0; mi < 4; ++mi)                   \
        _Pragma("unroll") for (int ni = 0; ni < 2; ++ni)                   \
            acc[MH * 4 + mi][NH * 2 + ni] =                                \
        __builtin_amdgcn_mfma_f32_16x16x32_f16(                            \
            AV[mi * 2 + ks], BV[ni * 2 + ks], acc[MH * 4 + mi][NH * 2 + ni], 0, 0, 0); \
    __builtin_amdgcn_s_setprio(0);                                         \
  } while (0)

template <int MODE>
__device__ __forceinline__ void gemm8_body(
    const u16* __restrict__ A0, const u16* __restrict__ A1,
    const u16* __restrict__ B0, const u16* __restrict__ B1,
    u16* __restrict__ Oh, u16* __restrict__ Ol, u16* __restrict__ E,
    float2* __restrict__ PS, int n0) {
  constexpr int NT = 32;  // K-tiles of 64 (2 segments x 16)
  constexpr int NI = NT / 2;
  constexpr int SA = 2048, SB = 2048;
  constexpr int GXL = (MODE == 0) ? 2 : 3;
  __shared__ u16 lds[65536];

  const int nwg = gridDim.x * gridDim.y * gridDim.z;
  int lin = ((int)blockIdx.z * gridDim.y + blockIdx.y) * gridDim.x + blockIdx.x;
  int swz = (lin & 7) * (nwg >> 3) + (lin >> 3);
  const int bx = swz & ((1 << GXL) - 1);
  int rem = swz >> GXL;
  const int by = (MODE == 0) ? rem : (rem & 7);
  const int bz = (MODE == 0) ? 0 : (rem >> 3);

  const int zn = bz;
  const int row0 = by * 256;
  const int col0 = bx * 256;
  const char *aB0, *aB1, *bB0, *bB1;
  if constexpr (MODE == 0) {
    aB0 = (const char*)(A0 + (size_t)row0 * C);   // xh16 rows
    aB1 = (const char*)(A1 + (size_t)row0 * C);   // (same)
    bB0 = (const char*)(B0 + (size_t)col0 * C);   // MTh rows
    bB1 = (const char*)(B1 + (size_t)col0 * C);   // MTl rows
  } else {
    const int n = n0 + zn;
    aB0 = (const char*)(A0 + ((size_t)n * L + row0) * C);  // Ph
    aB1 = (const char*)(A1 + ((size_t)n * L + row0) * C);  // Pl
    bB0 = (const char*)(B0 + ((size_t)n * L + col0) * C);  // xh16
    bB1 = (const char*)(B1 + ((size_t)n * L + col0) * C);  // (same)
  }

  const int t = threadIdx.x;
  const int lane = t & 63, w = t >> 6;
  const int wr = w >> 2, wc = w & 3;
  const int lr = lane & 15, lk = lane >> 4;

  const int rp0 = w * 8 + (lane >> 3);
  const int rp1 = 64 + rp0;
  const int g = (lane & 7) ^ ((lane >> 3) & 7);
  const int dO0 = w * 512 + (lane >> 3) * 64 + (lane & 7) * 8;
  const int dO1 = 4096 + dO0;
  const int sA0_0 = ((rp0 & 63) | ((rp0 >> 6) << 7)) * SA + g * 16;
  const int sA0_1 = ((rp1 & 63) | ((rp1 >> 6) << 7)) * SA + g * 16;
  const int sA1_0 = (((rp0 & 63) | 64) | ((rp0 >> 6) << 7)) * SA + g * 16;
  const int sA1_1 = (((rp1 & 63) | 64) | ((rp1 >> 6) << 7)) * SA + g * 16;
  const int sB0_0 = ((rp0 & 31) | ((rp0 >> 5) << 6)) * SB + g * 16;
  const int sB0_1 = ((rp1 & 31) | ((rp1 >> 5) << 6)) * SB + g * 16;
  const int sB1_0 = (((rp0 & 31) | 32) | ((rp0 >> 5) << 6)) * SB + g * 16;
  const int sB1_1 = (((rp1 & 31) | 32) | ((rp1 >> 5) << 6)) * SB + g * 16;

  auto stage = [&](int kt, int so0, int so1, int rbase, bool isB) {
    const int seg = kt >> 4;  // 2 segments x 16 K-tiles
    const char* p = isB ? (seg == 1 ? bB1 : bB0) : (seg == 1 ? aB1 : aB0);
    const int kOff = (kt & 15) * 128;
    u16* dst = &lds[(kt & 1) * 32768 + rbase];
    gload16(p + kOff + so0, dst + dO0);
    gload16(p + kOff + so1, dst + dO1);
  };

  auto dsA = [&](int d, int mh, f16x8* av) {
#pragma unroll
    for (int mi = 0; mi < 4; ++mi)
#pragma unroll
      for (int ks = 0; ks < 2; ++ks)
        av[mi * 2 + ks] = *(const f16x8*)&lds[d * 32768 + mh * 8192 +
                                              (wr * 64 + mi * 16 + lr) * 64 +
                                              (((ks * 4 + lk) ^ (lr & 7)) * 8)];
  };
  auto dsB = [&](int d, int nh, f16x8* bv) {
#pragma unroll
    for (int ni = 0; ni < 2; ++ni)
#pragma unroll
      for (int ks = 0; ks < 2; ++ks)
        bv[ni * 2 + ks] = *(const f16x8*)&lds[d * 32768 + 16384 + nh * 8192 +
                                              (wc * 32 + ni * 16 + lr) * 64 +
                                              (((ks * 4 + lk) ^ (lr & 7)) * 8)];
  };

  f32x4 acc[8][4] = {};
  f16x8 av[8], b0v[4], b1v[4];

  // prologue: t0 fully + t1.{A0,B0}; b0v read AFTER the certifying barrier.
  stage(0, sA0_0, sA0_1, 0, false);
  stage(0, sB0_0, sB0_1, 16384, true);
  stage(0, sA1_0, sA1_1, 8192, false);
  stage(0, sB1_0, sB1_1, 24576, true);
  stage(1, sA0_0, sA0_1, 0, false);
  stage(1, sB0_0, sB0_1, 16384, true);
  VMCNT4();
  PH_CLOSE();
  dsB(0, 0, b0v);

  for (int i = 0; i < NI; ++i) {
    const int t1 = 2 * i + 1, t2 = 2 * i + 2, t3 = 2 * i + 3;
    // ph1: Q(0,0) d0  [8 reads]
    dsA(0, 0, av);
    stage(t1, sA1_0, sA1_1, 8192, false);
    PH_OPEN();
    MFMAQ(0, 0, av, b0v);
    PH_CLOSE();
    // ph2: Q(0,1) d0  [4 reads]
    dsB(0, 1, b1v);
    stage(t1, sB1_0, sB1_1, 24576, true);
    PH_OPEN();
    MFMAQ(0, 1, av, b1v);
    PH_CLOSE();
    // ph3: Q(1,0) d0  [8 reads]
    dsA(0, 1, av);
    if (t2 < NT) stage(t2, sA0_0, sA0_1, 0, false);
    PH_OPEN();
    MFMAQ(1, 0, av, b0v);
    PH_CLOSE();
    // ph4: Q(1,1) d0; d1 certified after this barrier -> in-window b0v read.
    if (t2 < NT) {
      stage(t2, sB0_0, sB0_1, 16384, true);
      VMCNT4();
    } else {
      VMCNT0();
    }
    PH_OPEN();
    dsB(1, 0, b0v);
    MFMAQ(1, 1, av, b1v);
    PH_CLOSE();
    // ph5: Q(0,0) d1  [8 reads]
    dsA(1, 0, av);
    if (t2 < NT) stage(t2, sA1_0, sA1_1, 8192, false);
    PH_OPEN();
    MFMAQ(0, 0, av, b0v);
    PH_CLOSE();
    // ph6: Q(0,1) d1  [4 reads]
    dsB(1, 1, b1v);
    if (t2 < NT) stage(t2, sB1_0, sB1_1, 24576, true);
    PH_OPEN();
    MFMAQ(0, 1, av, b1v);
    PH_CLOSE();
    // ph7: Q(1,0) d1  [8 reads]
    dsA(1, 1, av);
    if (t3 < NT) stage(t3, sA0_0, sA0_1, 0, false);
    PH_OPEN();
    MFMAQ(1, 0, av, b0v);
    PH_CLOSE();
    // ph8: Q(1,1) d1; next d0 certified after this barrier -> in-window read.
    if (t3 < NT) {
      stage(t3, sB0_0, sB0_1, 16384, true);
      VMCNT4();
    } else {
      VMCNT0();
    }
    PH_OPEN();
    dsB(0, 0, b0v);  // garbage on final iteration, unused
    MFMAQ(1, 1, av, b1v);
    PH_CLOSE();
  }
  asm volatile("s_waitcnt lgkmcnt(0)" ::: "memory");

  // ------------------------------------------------------------ epilogue
  if constexpr (MODE == 0) {
#pragma unroll
    for (int mg = 0; mg < 8; ++mg)
#pragma unroll
      for (int ng = 0; ng < 4; ++ng) {
        const int r = row0 + wr * 128 + (mg >> 2) * 64 + (mg & 3) * 16 + lk * 4;
        const int c = col0 + wc * 64 + (ng >> 1) * 32 + (ng & 1) * 16 + lr;
        const f32x4 v = acc[mg][ng];
#pragma unroll
        for (int j = 0; j < 4; ++j) {
          u16 h, l;
          split16(v[j], h, l);
          Oh[(size_t)(r + j) * C + c] = h;
          Ol[(size_t)(r + j) * C + c] = l;
        }
      }
  } else {
    // e-value epilogue: block col-max (LDS reduce), then e = exp(S-bm) bf16,
    // per-thread sums -> block stats PS = (bm, sum_e) per (col, by).
    const int gn = n0 + zn;
    float* sm_ = (float*)lds;          // [256 cols][stride 9] maxes
    float* ss_ = (float*)lds + 2304;   // [256 cols][stride 9] sums
#pragma unroll
    for (int ng = 0; ng < 4; ++ng) {
      float mx = -3.0e38f;
#pragma unroll
      for (int mg = 0; mg < 8; ++mg)
#pragma unroll
        for (int j = 0; j < 4; ++j) mx = fmaxf(mx, acc[mg][ng][j]);
      const int cl = wc * 64 + (ng >> 1) * 32 + (ng & 1) * 16 + lr;
      sm_[cl * 9 + wr * 4 + lk] = mx;
    }
    __syncthreads();
#pragma unroll
    for (int ng = 0; ng < 4; ++ng) {
      const int cl = wc * 64 + (ng >> 1) * 32 + (ng & 1) * 16 + lr;
      float bm = -3.0e38f;
#pragma unroll
      for (int s = 0; s < 8; ++s) bm = fmaxf(bm, sm_[cl * 9 + s]);
      float sum = 0.f;
#pragma unroll
      for (int mg = 0; mg < 8; ++mg) {
        const int r = row0 + wr * 128 + (mg >> 2) * 64 + (mg & 3) * 16 + lk * 4;
#pragma unroll
        for (int j = 0; j < 4; ++j) {
          float ev = __expf(acc[mg][ng][j] - bm);
          sum += ev;
          E[((size_t)zn * L + r + j) * L + col0 + cl] = f2bf(ev);
        }
      }
      ss_[cl * 9 + wr * 4 + lk] = sum;
    }
    __syncthreads();
    if (t < 256) {
      float bm = -3.0e38f, sum = 0.f;
#pragma unroll
      for (int s = 0; s < 8; ++s) {
        bm = fmaxf(bm, sm_[t * 9 + s]);
        sum += ss_[t * 9 + s];
      }
      PS[((size_t)gn * L + col0 + t) * 8 + by] = make_float2(bm, sum);
    }
  }
}

__global__ __launch_bounds__(512, 2) void g_p(
    const u16* A0, const u16* A1, const u16* B0, const u16* B1,
    u16* Oh, u16* Ol) {
  gemm8_body<0>(A0, A1, B0, B1, Oh, Ol, nullptr, nullptr, 0);
}
__global__ __launch_bounds__(512, 2) void g_sc(
    const u16* A0, const u16* A1, const u16* B0, const u16* B1,
    u16* E, float2* PS, int n0) {
  gemm8_body<1>(A0, A1, B0, B1, nullptr, nullptr, E, PS, n0);
}

// ---------------------- stats merge -> per-(segment, col) rescale factors
__global__ __launch_bounds__(256) void stats_merge(const float2* __restrict__ pstats,
                                                   float* __restrict__ fac,
                                                   int n0) {
  const int gn = n0 + blockIdx.z;
  const int m = blockIdx.x * 256 + threadIdx.x;
  const float2* p = &pstats[((size_t)gn * L + m) * 8];
  float2 pv[8];
  float gm = -3.0e38f;
#pragma unroll
  for (int j = 0; j < 8; ++j) { pv[j] = p[j]; gm = fmaxf(gm, pv[j].x); }
  float gs = 0.f;
#pragma unroll
  for (int j = 0; j < 8; ++j) gs += pv[j].y * __expf(pv[j].x - gm);
  const float inv = 1.f / gs;
#pragma unroll
  for (int s = 0; s < 8; ++s)
    fac[((size_t)gn * 8 + s) * L + m] = __expf(pv[s].x - gm) * inv;
}

// ------------------------------- out GEMM (bf16 e * fac staging, 128x256)
__global__ __launch_bounds__(512, 4) void gemm_out_k(
    const u16* __restrict__ e, const float* __restrict__ fac,
    const u16* __restrict__ xT, float* __restrict__ out, int n0) {
  __shared__ u16 lA[128 * 64];
  __shared__ u16 lB[256 * 64];
  const int nwg = gridDim.x * gridDim.y * gridDim.z;
  int lin = ((int)blockIdx.z * gridDim.y + blockIdx.y) * gridDim.x + blockIdx.x;
  int swz = (lin & 7) * (nwg >> 3) + (lin >> 3);
  const int bx = swz & 3, by = (swz >> 2) & 15, bz = swz >> 6;
  const int zn = bz, gn = n0 + zn;
  const int row0 = by * 128, col0 = bx * 256;
  const u16* Ee = e + (size_t)zn * L * L + (size_t)row0 * L;
  const float* fr = fac + ((size_t)gn * 8 + (by >> 1)) * L;
  const char* bB = (const char*)(xT + ((size_t)gn * C + col0) * L);
  float* O = out + ((size_t)gn * L + row0) * C + col0;

  const int t = threadIdx.x;
  const int lane = t & 63, w = t >> 6;
  const int wr = w >> 2, wc = w & 3;
  const int lr = lane & 15, lk = lane >> 4;
  const int c4 = t & 15, rb4 = t >> 4;
  const int gB = (t & 7) ^ ((t >> 3) & 7);
  const int Rb = t >> 3;

  auto aoff = [&](int r, int k) { return r * 64 + (((k >> 3) ^ (r & 7)) << 3) + (k & 7); };

  ushort4 ev4[4];
  float4 fv;
  auto loadA = [&](int kt) {
#pragma unroll
    for (int i = 0; i < 4; ++i)
      ev4[i] = *(const ushort4*)&Ee[(size_t)(rb4 + i * 32) * L + kt * 64 + c4 * 4];
    fv = *(const float4*)&fr[kt * 64 + c4 * 4];
  };

  f32x4 acc[4][4] = {};
  loadA(0);
  for (int kt = 0; kt < 32; ++kt) {
    ushort4 pk[4];
#pragma unroll
    for (int i = 0; i < 4; ++i) {
      pk[i].x = f2bf(bf2f(ev4[i].x) * fv.x);
      pk[i].y = f2bf(bf2f(ev4[i].y) * fv.y);
      pk[i].z = f2bf(bf2f(ev4[i].z) * fv.z);
      pk[i].w = f2bf(bf2f(ev4[i].w) * fv.w);
    }
    __syncthreads();
#pragma unroll
    for (int i = 0; i < 4; ++i)
      *(ushort4*)&lA[aoff(rb4 + i * 32, c4 * 4)] = pk[i];
#pragma unroll
    for (int i = 0; i < 4; ++i)
      gload16(bB + (size_t)(Rb + i * 64) * (L * 2) + kt * 128 + gB * 16,
              &lB[(Rb + i * 64) * 64 + (t & 7) * 8]);
    if (kt < 31) {
      loadA(kt + 1);  // 5 vmem after the 4 B-gloads
      asm volatile("s_waitcnt vmcnt(5) lgkmcnt(0)" ::: "memory");
    } else {
      asm volatile("s_waitcnt vmcnt(0) lgkmcnt(0)" ::: "memory");
    }
    __syncthreads();
#pragma unroll
    for (int ks = 0; ks < 2; ++ks) {
      s16x8 bf[4];
#pragma unroll
      for (int ni = 0; ni < 4; ++ni)
        bf[ni] = *(const s16x8*)&lB[aoff(wc * 64 + ni * 16 + lr, ks * 32 + lk * 8)];
      __builtin_amdgcn_s_setprio(1);
#pragma unroll
      for (int mi = 0; mi < 4; ++mi) {
        s16x8 af = *(const s16x8*)&lA[aoff(wr * 64 + mi * 16 + lr, ks * 32 + lk * 8)];
#pragma unroll
        for (int ni = 0; ni < 4; ++ni)
          acc[mi][ni] = __builtin_amdgcn_mfma_f32_16x16x32_bf16(af, bf[ni], acc[mi][ni], 0, 0, 0);
      }
      __builtin_amdgcn_s_setprio(0);
    }
  }
#pragma unroll
  for (int mi = 0; mi < 4; ++mi)
#pragma unroll
    for (int ni = 0; ni < 4; ++ni)
#pragma unroll
      for (int j = 0; j < 4; ++j)
        O[(size_t)(wr * 64 + mi * 16 + lk * 4 + j) * C + wc * 64 + ni * 16 + lr] =
            acc[mi][ni][j];
}

// ----------------------------------------------------------------- launch
extern "C" void kernel_launch(void* const* d_in, const int* in_sizes, int n_in,
                              void* d_out, int out_size, void* d_ws, size_t ws_size,
                              hipStream_t stream) {
  const float* x = (const float*)d_in[0];
  const float* Wq = (const float*)d_in[1];
  const float* Wk = (const float*)d_in[2];
  float* out = (float*)d_out;

  char* ws = (char*)d_ws;
  size_t off = 0;
  auto alloc = [&](size_t bytes) -> void* {
    void* p = ws + off;
    off = (off + bytes + 255) & ~(size_t)255;
    return p;
  };
  u16* MTh = (u16*)alloc((size_t)C * C * 2);
  u16* MTl = (u16*)alloc((size_t)C * C * 2);
  u16* WqTh = (u16*)alloc((size_t)C * C * 2);
  u16* WqTl = (u16*)alloc((size_t)C * C * 2);
  u16* WkTh = (u16*)alloc((size_t)C * C * 2);
  u16* WkTl = (u16*)alloc((size_t)C * C * 2);
  u16* xh = (u16*)alloc((size_t)NL * C * 2);   // fp16 x
  u16* xT = (u16*)alloc((size_t)N * C * L * 2);  // bf16 x^T
  u16* Ph = (u16*)alloc((size_t)NL * C * 2);   // fp16 hi
  u16* Pl = (u16*)alloc((size_t)NL * C * 2);   // fp16 lo
  float2* pstats = (float2*)alloc((size_t)N * L * 8 * 8);
  float* fac = (float*)alloc((size_t)N * 8 * L * 4);
  const size_t base = off;
  const size_t per_n = (size_t)L * L * 2;  // bf16 e-values
  size_t avail = ws_size > base ? ws_size - base : 0;
  int chunk = (int)(avail / per_n);
  if (chunk < 1) chunk = 1;
  if (chunk > 16) chunk = 16;
  u16* e = (u16*)(ws + base);

  xprep<<<dim3(L / 64, C / 64, N), dim3(256), 0, stream>>>(x, xh, xT);
  transpose_w<<<dim3(16, 16, 2), dim3(256), 0, stream>>>(Wq, Wk, WqTh, WqTl, WkTh, WkTl);
  g_m<<<dim3(16, 16), dim3(256), 0, stream>>>(WqTh, WqTl, WkTh, WkTl, MTh, MTl);
  g_p<<<dim3(4, 128), dim3(512), 0, stream>>>(xh, xh, MTh, MTl, Ph, Pl);
  for (int n0 = 0; n0 < N; n0 += chunk) {
    int cn = (N - n0) < chunk ? (N - n0) : chunk;
    g_sc<<<dim3(8, 8, cn), dim3(512), 0, stream>>>(Ph, Pl, xh, xh, e, pstats, n0);
    stats_merge<<<dim3(L / 256, 1, cn), dim3(256), 0, stream>>>(pstats, fac, n0);
    gemm_out_k<<<dim3(4, 16, cn), dim3(512), 0, stream>>>(e, fac, xT, out, n0);
  }
}

// Round 14
// 559.002 us; speedup vs baseline: 1.8704x; 1.1813x over previous
//
#include <hip/hip_runtime.h>

typedef unsigned short u16;
typedef __attribute__((ext_vector_type(4))) float f32x4;
typedef __attribute__((ext_vector_type(8))) short s16x8;
typedef _Float16 f16x8 __attribute__((ext_vector_type(8)));

constexpr int N = 16, L = 2048, C = 1024;
constexpr int NL = N * L;

__device__ __forceinline__ u16 f2bf(float v) {
  unsigned u = __float_as_uint(v);
  return (u16)((u + 0x7FFFu + ((u >> 16) & 1u)) >> 16);
}
__device__ __forceinline__ u16 f2h(float v) {
  _Float16 h = (_Float16)v;
  return __builtin_bit_cast(u16, h);
}
__device__ __forceinline__ float bf2f(u16 h) { return __uint_as_float(((unsigned)h) << 16); }

__device__ __forceinline__ void gload16(const void* g, const void* l) {
  __builtin_amdgcn_global_load_lds((const __attribute__((address_space(1))) void*)g,
                                   (__attribute__((address_space(3))) void*)l, 16, 0, 0);
}

// ------------------------------------------------- fused x preprocessing
// x [N][L][C] fp32 -> xh16 (fp16, same layout) + xT [N][C][L] bf16
__global__ __launch_bounds__(256) void xprep(const float* __restrict__ x,
                                             u16* __restrict__ xh,
                                             u16* __restrict__ xT) {
  __shared__ u16 tile[64 * 68];
  const int n = blockIdx.z;
  const int l0 = blockIdx.x * 64;
  const int c0 = blockIdx.y * 64;
  const int t = threadIdx.x;
  const int cg = t & 15, r = t >> 4;
#pragma unroll
  for (int i = 0; i < 4; ++i) {
    int rr = r + i * 16;
    size_t idx = ((size_t)n * L + l0 + rr) * C + c0 + cg * 4;
    float4 v = *(const float4*)&x[idx];
    ushort4 h;
    h.x = f2h(v.x); h.y = f2h(v.y); h.z = f2h(v.z); h.w = f2h(v.w);
    *(ushort4*)&xh[idx] = h;
    ushort4 b;
    b.x = f2bf(v.x); b.y = f2bf(v.y); b.z = f2bf(v.z); b.w = f2bf(v.w);
    *(ushort4*)&tile[rr * 68 + cg * 4] = b;
  }
  __syncthreads();
  const int l4 = (t & 15) * 4;
#pragma unroll
  for (int i = 0; i < 4; ++i) {
    int cc = (t >> 4) + i * 16;
    ushort4 o;
    o.x = tile[(l4 + 0) * 68 + cc];
    o.y = tile[(l4 + 1) * 68 + cc];
    o.z = tile[(l4 + 2) * 68 + cc];
    o.w = tile[(l4 + 3) * 68 + cc];
    *(ushort4*)&xT[((size_t)n * C + c0 + cc) * L + l0 + l4] = o;
  }
}

// --------------------------------------- W transpose + bf16 hi/lo split
// (hi/lo needed only for the tiny fp32-accurate g_m)
__global__ __launch_bounds__(256) void transpose_w(
    const float* __restrict__ Wq, const float* __restrict__ Wk,
    u16* __restrict__ WqTh, u16* __restrict__ WqTl,
    u16* __restrict__ WkTh, u16* __restrict__ WkTl) {
  __shared__ u16 th[64 * 68], tl[64 * 68];
  const float* W = blockIdx.z ? Wk : Wq;
  u16* Th = blockIdx.z ? WkTh : WqTh;
  u16* Tl = blockIdx.z ? WkTl : WqTl;
  const int a0 = blockIdx.x * 64, c0 = blockIdx.y * 64;
  const int t = threadIdx.x, cg = t & 15, r = t >> 4;
#pragma unroll
  for (int i = 0; i < 4; ++i) {
    int rr = r + i * 16;
    float4 v = *(const float4*)&W[(size_t)(a0 + rr) * C + c0 + cg * 4];
    ushort4 h, l;
    h.x = f2bf(v.x); l.x = f2bf(v.x - bf2f(h.x));
    h.y = f2bf(v.y); l.y = f2bf(v.y - bf2f(h.y));
    h.z = f2bf(v.z); l.z = f2bf(v.z - bf2f(h.z));
    h.w = f2bf(v.w); l.w = f2bf(v.w - bf2f(h.w));
    *(ushort4*)&th[rr * 68 + cg * 4] = h;
    *(ushort4*)&tl[rr * 68 + cg * 4] = l;
  }
  __syncthreads();
  const int a4 = (t & 15) * 4;
#pragma unroll
  for (int i = 0; i < 4; ++i) {
    int cc = (t >> 4) + i * 16;
    ushort4 oh, ol;
    oh.x = th[(a4 + 0) * 68 + cc]; ol.x = tl[(a4 + 0) * 68 + cc];
    oh.y = th[(a4 + 1) * 68 + cc]; ol.y = tl[(a4 + 1) * 68 + cc];
    oh.z = th[(a4 + 2) * 68 + cc]; ol.z = tl[(a4 + 2) * 68 + cc];
    oh.w = th[(a4 + 3) * 68 + cc]; ol.w = tl[(a4 + 3) * 68 + cc];
    *(ushort4*)&Th[(size_t)(c0 + cc) * C + a0 + a4] = oh;
    *(ushort4*)&Tl[(size_t)(c0 + cc) * C + a0 + a4] = ol;
  }
}

// ------------------- MT = Wq^T * Wk (bf16 3-pass, tiny) -> fp16 out
__global__ __launch_bounds__(256) void g_m(
    const u16* __restrict__ Ah, const u16* __restrict__ Al,
    const u16* __restrict__ Bh, const u16* __restrict__ Bl,
    u16* __restrict__ Mh) {
  __shared__ u16 sAh[64 * 64], sAl[64 * 64], sBh[64 * 64], sBl[64 * 64];
  const int i0 = blockIdx.y * 64, j0 = blockIdx.x * 64;
  const int t = threadIdx.x, lane = t & 63, w = t >> 6;
  const int wr = w >> 1, wc = w & 1;
  const int lr = lane & 15, lk = lane >> 4;
  const int g8 = t & 7, rb = t >> 3;
  f32x4 acc[2][2] = {};
  for (int kk = 0; kk < C; kk += 64) {
    __syncthreads();
#pragma unroll
    for (int i = 0; i < 2; ++i) {
      int r = rb + i * 32;
      *(uint4*)&sAh[r * 64 + g8 * 8] = *(const uint4*)&Ah[(size_t)(i0 + r) * C + kk + g8 * 8];
      *(uint4*)&sAl[r * 64 + g8 * 8] = *(const uint4*)&Al[(size_t)(i0 + r) * C + kk + g8 * 8];
      *(uint4*)&sBh[r * 64 + g8 * 8] = *(const uint4*)&Bh[(size_t)(j0 + r) * C + kk + g8 * 8];
      *(uint4*)&sBl[r * 64 + g8 * 8] = *(const uint4*)&Bl[(size_t)(j0 + r) * C + kk + g8 * 8];
    }
    __syncthreads();
#pragma unroll
    for (int ks = 0; ks < 2; ++ks)
#pragma unroll
      for (int mi = 0; mi < 2; ++mi) {
        s16x8 ah = *(const s16x8*)&sAh[(wr * 32 + mi * 16 + lr) * 64 + ks * 32 + lk * 8];
        s16x8 al = *(const s16x8*)&sAl[(wr * 32 + mi * 16 + lr) * 64 + ks * 32 + lk * 8];
#pragma unroll
        for (int ni = 0; ni < 2; ++ni) {
          s16x8 bh = *(const s16x8*)&sBh[(wc * 32 + ni * 16 + lr) * 64 + ks * 32 + lk * 8];
          s16x8 bl = *(const s16x8*)&sBl[(wc * 32 + ni * 16 + lr) * 64 + ks * 32 + lk * 8];
          acc[mi][ni] = __builtin_amdgcn_mfma_f32_16x16x32_bf16(ah, bh, acc[mi][ni], 0, 0, 0);
          acc[mi][ni] = __builtin_amdgcn_mfma_f32_16x16x32_bf16(ah, bl, acc[mi][ni], 0, 0, 0);
          acc[mi][ni] = __builtin_amdgcn_mfma_f32_16x16x32_bf16(al, bh, acc[mi][ni], 0, 0, 0);
        }
      }
  }
#pragma unroll
  for (int mi = 0; mi < 2; ++mi)
#pragma unroll
    for (int ni = 0; ni < 2; ++ni)
#pragma unroll
      for (int j = 0; j < 4; ++j) {
        int rr = i0 + wr * 32 + mi * 16 + lk * 4 + j;
        int cc = j0 + wc * 32 + ni * 16 + lr;
        Mh[(size_t)rr * C + cc] = f2h(acc[mi][ni][j]);
      }
}

// --------------- 8-phase 256x256 fp16 GEMM, single-pass (K=C), R11 schedule
// MODE 0 (P):      P[nl][c'] = sum_c xh16[nl][c]*MTh[c'][c]; out fp16.
// MODE 1 (SCORES): S[l][m] = sum_c Ph[l][c]*xh16[m][c]; out bf16 e-values
//                  exp(S - blockmax) + block stats (bm, sum_e) per (col, by).
#define PH_OPEN() asm volatile("s_barrier" ::: "memory")
#define PH_CLOSE() asm volatile("s_barrier" ::: "memory")
#define VMCNT4() asm volatile("s_waitcnt vmcnt(4)" ::: "memory")
#define VMCNT0() asm volatile("s_waitcnt vmcnt(0)" ::: "memory")

#define MFMAQ(MH, NH, AV, BV)                                              \
  do {                                                                     \
    __builtin_amdgcn_s_setprio(1);                                         \
    _Pragma("unroll") for (int ks = 0; ks < 2; ++ks)                       \
        _Pragma("unroll") for (int mi = 0; mi < 4; ++mi)                   \
        _Pragma("unroll") for (int ni = 0; ni < 2; ++ni)                   \
            acc[MH * 4 + mi][NH * 2 + ni] =                                \
        __builtin_amdgcn_mfma_f32_16x16x32_f16(                            \
            AV[mi * 2 + ks], BV[ni * 2 + ks], acc[MH * 4 + mi][NH * 2 + ni], 0, 0, 0); \
    __builtin_amdgcn_s_setprio(0);                                         \
  } while (0)

template <int MODE>
__device__ __forceinline__ void gemm8_body(
    const u16* __restrict__ A0, const u16* __restrict__ B0,
    u16* __restrict__ Oh, u16* __restrict__ E,
    float2* __restrict__ PS, int n0) {
  constexpr int NT = 16;  // K-tiles of 64, K = C = 1024
  constexpr int NI = NT / 2;
  constexpr int SA = 2048, SB = 2048;
  constexpr int GXL = (MODE == 0) ? 2 : 3;
  __shared__ u16 lds[65536];

  const int nwg = gridDim.x * gridDim.y * gridDim.z;
  int lin = ((int)blockIdx.z * gridDim.y + blockIdx.y) * gridDim.x + blockIdx.x;
  int swz = (lin & 7) * (nwg >> 3) + (lin >> 3);
  const int bx = swz & ((1 << GXL) - 1);
  int rem = swz >> GXL;
  const int by = (MODE == 0) ? rem : (rem & 7);
  const int bz = (MODE == 0) ? 0 : (rem >> 3);

  const int zn = bz;
  const int row0 = by * 256;
  const int col0 = bx * 256;
  const char *aB0, *bB0;
  if constexpr (MODE == 0) {
    aB0 = (const char*)(A0 + (size_t)row0 * C);   // xh16 rows
    bB0 = (const char*)(B0 + (size_t)col0 * C);   // MTh rows
  } else {
    const int n = n0 + zn;
    aB0 = (const char*)(A0 + ((size_t)n * L + row0) * C);  // Ph
    bB0 = (const char*)(B0 + ((size_t)n * L + col0) * C);  // xh16
  }

  const int t = threadIdx.x;
  const int lane = t & 63, w = t >> 6;
  const int wr = w >> 2, wc = w & 3;
  const int lr = lane & 15, lk = lane >> 4;

  const int rp0 = w * 8 + (lane >> 3);
  const int rp1 = 64 + rp0;
  const int g = (lane & 7) ^ ((lane >> 3) & 7);
  const int dO0 = w * 512 + (lane >> 3) * 64 + (lane & 7) * 8;
  const int dO1 = 4096 + dO0;
  const int sA0_0 = ((rp0 & 63) | ((rp0 >> 6) << 7)) * SA + g * 16;
  const int sA0_1 = ((rp1 & 63) | ((rp1 >> 6) << 7)) * SA + g * 16;
  const int sA1_0 = (((rp0 & 63) | 64) | ((rp0 >> 6) << 7)) * SA + g * 16;
  const int sA1_1 = (((rp1 & 63) | 64) | ((rp1 >> 6) << 7)) * SA + g * 16;
  const int sB0_0 = ((rp0 & 31) | ((rp0 >> 5) << 6)) * SB + g * 16;
  const int sB0_1 = ((rp1 & 31) | ((rp1 >> 5) << 6)) * SB + g * 16;
  const int sB1_0 = (((rp0 & 31) | 32) | ((rp0 >> 5) << 6)) * SB + g * 16;
  const int sB1_1 = (((rp1 & 31) | 32) | ((rp1 >> 5) << 6)) * SB + g * 16;

  auto stage = [&](int kt, int so0, int so1, int rbase, bool isB) {
    const char* p = isB ? bB0 : aB0;
    const int kOff = kt * 128;
    u16* dst = &lds[(kt & 1) * 32768 + rbase];
    gload16(p + kOff + so0, dst + dO0);
    gload16(p + kOff + so1, dst + dO1);
  };

  auto dsA = [&](int d, int mh, f16x8* av) {
#pragma unroll
    for (int mi = 0; mi < 4; ++mi)
#pragma unroll
      for (int ks = 0; ks < 2; ++ks)
        av[mi * 2 + ks] = *(const f16x8*)&lds[d * 32768 + mh * 8192 +
                                              (wr * 64 + mi * 16 + lr) * 64 +
                                              (((ks * 4 + lk) ^ (lr & 7)) * 8)];
  };
  auto dsB = [&](int d, int nh, f16x8* bv) {
#pragma unroll
    for (int ni = 0; ni < 2; ++ni)
#pragma unroll
      for (int ks = 0; ks < 2; ++ks)
        bv[ni * 2 + ks] = *(const f16x8*)&lds[d * 32768 + 16384 + nh * 8192 +
                                              (wc * 32 + ni * 16 + lr) * 64 +
                                              (((ks * 4 + lk) ^ (lr & 7)) * 8)];
  };

  f32x4 acc[8][4] = {};
  f16x8 av[8], b0v[4], b1v[4];

  // prologue: t0 fully + t1.{A0,B0}; b0v read AFTER the certifying barrier.
  stage(0, sA0_0, sA0_1, 0, false);
  stage(0, sB0_0, sB0_1, 16384, true);
  stage(0, sA1_0, sA1_1, 8192, false);
  stage(0, sB1_0, sB1_1, 24576, true);
  stage(1, sA0_0, sA0_1, 0, false);
  stage(1, sB0_0, sB0_1, 16384, true);
  VMCNT4();
  PH_CLOSE();
  dsB(0, 0, b0v);

  for (int i = 0; i < NI; ++i) {
    const int t1 = 2 * i + 1, t2 = 2 * i + 2, t3 = 2 * i + 3;
    // ph1: Q(0,0) d0  [8 reads]
    dsA(0, 0, av);
    stage(t1, sA1_0, sA1_1, 8192, false);
    PH_OPEN();
    MFMAQ(0, 0, av, b0v);
    PH_CLOSE();
    // ph2: Q(0,1) d0  [4 reads]
    dsB(0, 1, b1v);
    stage(t1, sB1_0, sB1_1, 24576, true);
    PH_OPEN();
    MFMAQ(0, 1, av, b1v);
    PH_CLOSE();
    // ph3: Q(1,0) d0  [8 reads]
    dsA(0, 1, av);
    if (t2 < NT) stage(t2, sA0_0, sA0_1, 0, false);
    PH_OPEN();
    MFMAQ(1, 0, av, b0v);
    PH_CLOSE();
    // ph4: Q(1,1) d0; d1 certified after this barrier -> in-window b0v read.
    if (t2 < NT) {
      stage(t2, sB0_0, sB0_1, 16384, true);
      VMCNT4();
    } else {
      VMCNT0();
    }
    PH_OPEN();
    dsB(1, 0, b0v);
    MFMAQ(1, 1, av, b1v);
    PH_CLOSE();
    // ph5: Q(0,0) d1  [8 reads]
    dsA(1, 0, av);
    if (t2 < NT) stage(t2, sA1_0, sA1_1, 8192, false);
    PH_OPEN();
    MFMAQ(0, 0, av, b0v);
    PH_CLOSE();
    // ph6: Q(0,1) d1  [4 reads]
    dsB(1, 1, b1v);
    if (t2 < NT) stage(t2, sB1_0, sB1_1, 24576, true);
    PH_OPEN();
    MFMAQ(0, 1, av, b1v);
    PH_CLOSE();
    // ph7: Q(1,0) d1  [8 reads]
    dsA(1, 1, av);
    if (t3 < NT) stage(t3, sA0_0, sA0_1, 0, false);
    PH_OPEN();
    MFMAQ(1, 0, av, b0v);
    PH_CLOSE();
    // ph8: Q(1,1) d1; next d0 certified after this barrier -> in-window read.
    if (t3 < NT) {
      stage(t3, sB0_0, sB0_1, 16384, true);
      VMCNT4();
    } else {
      VMCNT0();
    }
    PH_OPEN();
    dsB(0, 0, b0v);  // garbage on final iteration, unused
    MFMAQ(1, 1, av, b1v);
    PH_CLOSE();
  }
  asm volatile("s_waitcnt lgkmcnt(0)" ::: "memory");

  // ------------------------------------------------------------ epilogue
  if constexpr (MODE == 0) {
#pragma unroll
    for (int mg = 0; mg < 8; ++mg)
#pragma unroll
      for (int ng = 0; ng < 4; ++ng) {
        const int r = row0 + wr * 128 + (mg >> 2) * 64 + (mg & 3) * 16 + lk * 4;
        const int c = col0 + wc * 64 + (ng >> 1) * 32 + (ng & 1) * 16 + lr;
        const f32x4 v = acc[mg][ng];
#pragma unroll
        for (int j = 0; j < 4; ++j)
          Oh[(size_t)(r + j) * C + c] = f2h(v[j]);
      }
  } else {
    // e-value epilogue: block col-max (LDS reduce), then e = exp(S-bm) bf16,
    // per-thread sums -> block stats PS = (bm, sum_e) per (col, by).
    const int gn = n0 + zn;
    float* sm_ = (float*)lds;          // [256 cols][stride 9] maxes
    float* ss_ = (float*)lds + 2304;   // [256 cols][stride 9] sums
#pragma unroll
    for (int ng = 0; ng < 4; ++ng) {
      float mx = -3.0e38f;
#pragma unroll
      for (int mg = 0; mg < 8; ++mg)
#pragma unroll
        for (int j = 0; j < 4; ++j) mx = fmaxf(mx, acc[mg][ng][j]);
      const int cl = wc * 64 + (ng >> 1) * 32 + (ng & 1) * 16 + lr;
      sm_[cl * 9 + wr * 4 + lk] = mx;
    }
    __syncthreads();
#pragma unroll
    for (int ng = 0; ng < 4; ++ng) {
      const int cl = wc * 64 + (ng >> 1) * 32 + (ng & 1) * 16 + lr;
      float bm = -3.0e38f;
#pragma unroll
      for (int s = 0; s < 8; ++s) bm = fmaxf(bm, sm_[cl * 9 + s]);
      float sum = 0.f;
#pragma unroll
      for (int mg = 0; mg < 8; ++mg) {
        const int r = row0 + wr * 128 + (mg >> 2) * 64 + (mg & 3) * 16 + lk * 4;
#pragma unroll
        for (int j = 0; j < 4; ++j) {
          float ev = __expf(acc[mg][ng][j] - bm);
          sum += ev;
          E[((size_t)zn * L + r + j) * L + col0 + cl] = f2bf(ev);
        }
      }
      ss_[cl * 9 + wr * 4 + lk] = sum;
    }
    __syncthreads();
    if (t < 256) {
      float bm = -3.0e38f, sum = 0.f;
#pragma unroll
      for (int s = 0; s < 8; ++s) {
        bm = fmaxf(bm, sm_[t * 9 + s]);
        sum += ss_[t * 9 + s];
      }
      PS[((size_t)gn * L + col0 + t) * 8 + by] = make_float2(bm, sum);
    }
  }
}

__global__ __launch_bounds__(512, 2) void g_p(
    const u16* A0, const u16* B0, u16* Oh) {
  gemm8_body<0>(A0, B0, Oh, nullptr, nullptr, 0);
}
__global__ __launch_bounds__(512, 2) void g_sc(
    const u16* A0, const u16* B0, u16* E, float2* PS, int n0) {
  gemm8_body<1>(A0, B0, nullptr, E, PS, n0);
}

// ---------------------- stats merge -> per-(segment, col) rescale factors
__global__ __launch_bounds__(256) void stats_merge(const float2* __restrict__ pstats,
                                                   float* __restrict__ fac,
                                                   int n0) {
  const int gn = n0 + blockIdx.z;
  const int m = blockIdx.x * 256 + threadIdx.x;
  const float2* p = &pstats[((size_t)gn * L + m) * 8];
  float2 pv[8];
  float gm = -3.0e38f;
#pragma unroll
  for (int j = 0; j < 8; ++j) { pv[j] = p[j]; gm = fmaxf(gm, pv[j].x); }
  float gs = 0.f;
#pragma unroll
  for (int j = 0; j < 8; ++j) gs += pv[j].y * __expf(pv[j].x - gm);
  const float inv = 1.f / gs;
#pragma unroll
  for (int s = 0; s < 8; ++s)
    fac[((size_t)gn * 8 + s) * L + m] = __expf(pv[s].x - gm) * inv;
}

// ------------------------------- out GEMM (bf16 e * fac staging, 128x256)
__global__ __launch_bounds__(512, 4) void gemm_out_k(
    const u16* __restrict__ e, const float* __restrict__ fac,
    const u16* __restrict__ xT, float* __restrict__ out, int n0) {
  __shared__ u16 lA[128 * 64];
  __shared__ u16 lB[256 * 64];
  const int nwg = gridDim.x * gridDim.y * gridDim.z;
  int lin = ((int)blockIdx.z * gridDim.y + blockIdx.y) * gridDim.x + blockIdx.x;
  int swz = (lin & 7) * (nwg >> 3) + (lin >> 3);
  const int bx = swz & 3, by = (swz >> 2) & 15, bz = swz >> 6;
  const int zn = bz, gn = n0 + zn;
  const int row0 = by * 128, col0 = bx * 256;
  const u16* Ee = e + (size_t)zn * L * L + (size_t)row0 * L;
  const float* fr = fac + ((size_t)gn * 8 + (by >> 1)) * L;
  const char* bB = (const char*)(xT + ((size_t)gn * C + col0) * L);
  float* O = out + ((size_t)gn * L + row0) * C + col0;

  const int t = threadIdx.x;
  const int lane = t & 63, w = t >> 6;
  const int wr = w >> 2, wc = w & 3;
  const int lr = lane & 15, lk = lane >> 4;
  const int c4 = t & 15, rb4 = t >> 4;
  const int gB = (t & 7) ^ ((t >> 3) & 7);
  const int Rb = t >> 3;

  auto aoff = [&](int r, int k) { return r * 64 + (((k >> 3) ^ (r & 7)) << 3) + (k & 7); };

  ushort4 ev4[4];
  float4 fv;
  auto loadA = [&](int kt) {
#pragma unroll
    for (int i = 0; i < 4; ++i)
      ev4[i] = *(const ushort4*)&Ee[(size_t)(rb4 + i * 32) * L + kt * 64 + c4 * 4];
    fv = *(const float4*)&fr[kt * 64 + c4 * 4];
  };

  f32x4 acc[4][4] = {};
  loadA(0);
  for (int kt = 0; kt < 32; ++kt) {
    ushort4 pk[4];
#pragma unroll
    for (int i = 0; i < 4; ++i) {
      pk[i].x = f2bf(bf2f(ev4[i].x) * fv.x);
      pk[i].y = f2bf(bf2f(ev4[i].y) * fv.y);
      pk[i].z = f2bf(bf2f(ev4[i].z) * fv.z);
      pk[i].w = f2bf(bf2f(ev4[i].w) * fv.w);
    }
    __syncthreads();
#pragma unroll
    for (int i = 0; i < 4; ++i)
      *(ushort4*)&lA[aoff(rb4 + i * 32, c4 * 4)] = pk[i];
#pragma unroll
    for (int i = 0; i < 4; ++i)
      gload16(bB + (size_t)(Rb + i * 64) * (L * 2) + kt * 128 + gB * 16,
              &lB[(Rb + i * 64) * 64 + (t & 7) * 8]);
    if (kt < 31) {
      loadA(kt + 1);  // 5 vmem after the 4 B-gloads
      asm volatile("s_waitcnt vmcnt(5) lgkmcnt(0)" ::: "memory");
    } else {
      asm volatile("s_waitcnt vmcnt(0) lgkmcnt(0)" ::: "memory");
    }
    __syncthreads();
#pragma unroll
    for (int ks = 0; ks < 2; ++ks) {
      s16x8 bf[4];
#pragma unroll
      for (int ni = 0; ni < 4; ++ni)
        bf[ni] = *(const s16x8*)&lB[aoff(wc * 64 + ni * 16 + lr, ks * 32 + lk * 8)];
      __builtin_amdgcn_s_setprio(1);
#pragma unroll
      for (int mi = 0; mi < 4; ++mi) {
        s16x8 af = *(const s16x8*)&lA[aoff(wr * 64 + mi * 16 + lr, ks * 32 + lk * 8)];
#pragma unroll
        for (int ni = 0; ni < 4; ++ni)
          acc[mi][ni] = __builtin_amdgcn_mfma_f32_16x16x32_bf16(af, bf[ni], acc[mi][ni], 0, 0, 0);
      }
      __builtin_amdgcn_s_setprio(0);
    }
  }
#pragma unroll
  for (int mi = 0; mi < 4; ++mi)
#pragma unroll
    for (int ni = 0; ni < 4; ++ni)
#pragma unroll
      for (int j = 0; j < 4; ++j)
        O[(size_t)(wr * 64 + mi * 16 + lk * 4 + j) * C + wc * 64 + ni * 16 + lr] =
            acc[mi][ni][j];
}

// ----------------------------------------------------------------- launch
extern "C" void kernel_launch(void* const* d_in, const int* in_sizes, int n_in,
                              void* d_out, int out_size, void* d_ws, size_t ws_size,
                              hipStream_t stream) {
  const float* x = (const float*)d_in[0];
  const float* Wq = (const float*)d_in[1];
  const float* Wk = (const float*)d_in[2];
  float* out = (float*)d_out;

  char* ws = (char*)d_ws;
  size_t off = 0;
  auto alloc = [&](size_t bytes) -> void* {
    void* p = ws + off;
    off = (off + bytes + 255) & ~(size_t)255;
    return p;
  };
  u16* MTh = (u16*)alloc((size_t)C * C * 2);
  u16* WqTh = (u16*)alloc((size_t)C * C * 2);
  u16* WqTl = (u16*)alloc((size_t)C * C * 2);
  u16* WkTh = (u16*)alloc((size_t)C * C * 2);
  u16* WkTl = (u16*)alloc((size_t)C * C * 2);
  u16* xh = (u16*)alloc((size_t)NL * C * 2);     // fp16 x
  u16* xT = (u16*)alloc((size_t)N * C * L * 2);  // bf16 x^T
  u16* Ph = (u16*)alloc((size_t)NL * C * 2);     // fp16 P
  float2* pstats = (float2*)alloc((size_t)N * L * 8 * 8);
  float* fac = (float*)alloc((size_t)N * 8 * L * 4);
  const size_t base = off;
  const size_t per_n = (size_t)L * L * 2;  // bf16 e-values
  size_t avail = ws_size > base ? ws_size - base : 0;
  int chunk = (int)(avail / per_n);
  if (chunk < 1) chunk = 1;
  if (chunk > 16) chunk = 16;
  u16* e = (u16*)(ws + base);

  xprep<<<dim3(L / 64, C / 64, N), dim3(256), 0, stream>>>(x, xh, xT);
  transpose_w<<<dim3(16, 16, 2), dim3(256), 0, stream>>>(Wq, Wk, WqTh, WqTl, WkTh, WkTl);
  g_m<<<dim3(16, 16), dim3(256), 0, stream>>>(WqTh, WqTl, WkTh, WkTl, MTh);
  g_p<<<dim3(4, 128), dim3(512), 0, stream>>>(xh, MTh, Ph);
  for (int n0 = 0; n0 < N; n0 += chunk) {
    int cn = (N - n0) < chunk ? (N - n0) : chunk;
    g_sc<<<dim3(8, 8, cn), dim3(512), 0, stream>>>(Ph, xh, e, pstats, n0);
    stats_merge<<<dim3(L / 256, 1, cn), dim3(256), 0, stream>>>(pstats, fac, n0);
    gemm_out_k<<<dim3(4, 16, cn), dim3(512), 0, stream>>>(e, fac, xT, out, n0);
  }
}

// Round 16
// 514.547 us; speedup vs baseline: 2.0320x; 1.0864x over previous
//
#include <hip/hip_runtime.h>

typedef unsigned short u16;
typedef __attribute__((ext_vector_type(4))) float f32x4;
typedef __attribute__((ext_vector_type(8))) short s16x8;
typedef _Float16 f16x8 __attribute__((ext_vector_type(8)));

constexpr int N = 16, L = 2048, C = 1024;
constexpr int NL = N * L;

__device__ __forceinline__ u16 f2bf(float v) {
  unsigned u = __float_as_uint(v);
  return (u16)((u + 0x7FFFu + ((u >> 16) & 1u)) >> 16);
}
__device__ __forceinline__ u16 f2h(float v) {
  _Float16 h = (_Float16)v;
  return __builtin_bit_cast(u16, h);
}
__device__ __forceinline__ float bf2f(u16 h) { return __uint_as_float(((unsigned)h) << 16); }

__device__ __forceinline__ void gload16(const void* g, const void* l) {
  __builtin_amdgcn_global_load_lds((const __attribute__((address_space(1))) void*)g,
                                   (__attribute__((address_space(3))) void*)l, 16, 0, 0);
}

// ------------------------------------------------- fused x preprocessing
// x [N][L][C] fp32 -> xh16 (fp16, same layout) + xT [N][C][L] bf16
__global__ __launch_bounds__(256) void xprep(const float* __restrict__ x,
                                             u16* __restrict__ xh,
                                             u16* __restrict__ xT) {
  __shared__ u16 tile[64 * 68];
  const int n = blockIdx.z;
  const int l0 = blockIdx.x * 64;
  const int c0 = blockIdx.y * 64;
  const int t = threadIdx.x;
  const int cg = t & 15, r = t >> 4;
#pragma unroll
  for (int i = 0; i < 4; ++i) {
    int rr = r + i * 16;
    size_t idx = ((size_t)n * L + l0 + rr) * C + c0 + cg * 4;
    float4 v = *(const float4*)&x[idx];
    ushort4 h;
    h.x = f2h(v.x); h.y = f2h(v.y); h.z = f2h(v.z); h.w = f2h(v.w);
    *(ushort4*)&xh[idx] = h;
    ushort4 b;
    b.x = f2bf(v.x); b.y = f2bf(v.y); b.z = f2bf(v.z); b.w = f2bf(v.w);
    *(ushort4*)&tile[rr * 68 + cg * 4] = b;
  }
  __syncthreads();
  const int l4 = (t & 15) * 4;
#pragma unroll
  for (int i = 0; i < 4; ++i) {
    int cc = (t >> 4) + i * 16;
    ushort4 o;
    o.x = tile[(l4 + 0) * 68 + cc];
    o.y = tile[(l4 + 1) * 68 + cc];
    o.z = tile[(l4 + 2) * 68 + cc];
    o.w = tile[(l4 + 3) * 68 + cc];
    *(ushort4*)&xT[((size_t)n * C + c0 + cc) * L + l0 + l4] = o;
  }
}

// --------------------------------------- W transpose + bf16 hi/lo split
__global__ __launch_bounds__(256) void transpose_w(
    const float* __restrict__ Wq, const float* __restrict__ Wk,
    u16* __restrict__ WqTh, u16* __restrict__ WqTl,
    u16* __restrict__ WkTh, u16* __restrict__ WkTl) {
  __shared__ u16 th[64 * 68], tl[64 * 68];
  const float* W = blockIdx.z ? Wk : Wq;
  u16* Th = blockIdx.z ? WkTh : WqTh;
  u16* Tl = blockIdx.z ? WkTl : WqTl;
  const int a0 = blockIdx.x * 64, c0 = blockIdx.y * 64;
  const int t = threadIdx.x, cg = t & 15, r = t >> 4;
#pragma unroll
  for (int i = 0; i < 4; ++i) {
    int rr = r + i * 16;
    float4 v = *(const float4*)&W[(size_t)(a0 + rr) * C + c0 + cg * 4];
    ushort4 h, l;
    h.x = f2bf(v.x); l.x = f2bf(v.x - bf2f(h.x));
    h.y = f2bf(v.y); l.y = f2bf(v.y - bf2f(h.y));
    h.z = f2bf(v.z); l.z = f2bf(v.z - bf2f(h.z));
    h.w = f2bf(v.w); l.w = f2bf(v.w - bf2f(h.w));
    *(ushort4*)&th[rr * 68 + cg * 4] = h;
    *(ushort4*)&tl[rr * 68 + cg * 4] = l;
  }
  __syncthreads();
  const int a4 = (t & 15) * 4;
#pragma unroll
  for (int i = 0; i < 4; ++i) {
    int cc = (t >> 4) + i * 16;
    ushort4 oh, ol;
    oh.x = th[(a4 + 0) * 68 + cc]; ol.x = tl[(a4 + 0) * 68 + cc];
    oh.y = th[(a4 + 1) * 68 + cc]; ol.y = tl[(a4 + 1) * 68 + cc];
    oh.z = th[(a4 + 2) * 68 + cc]; ol.z = tl[(a4 + 2) * 68 + cc];
    oh.w = th[(a4 + 3) * 68 + cc]; ol.w = tl[(a4 + 3) * 68 + cc];
    *(ushort4*)&Th[(size_t)(c0 + cc) * C + a0 + a4] = oh;
    *(ushort4*)&Tl[(size_t)(c0 + cc) * C + a0 + a4] = ol;
  }
}

// ------------------- MT = Wq^T * Wk (bf16 3-pass, tiny) -> fp16 out
__global__ __launch_bounds__(256) void g_m(
    const u16* __restrict__ Ah, const u16* __restrict__ Al,
    const u16* __restrict__ Bh, const u16* __restrict__ Bl,
    u16* __restrict__ Mh) {
  __shared__ u16 sAh[64 * 64], sAl[64 * 64], sBh[64 * 64], sBl[64 * 64];
  const int i0 = blockIdx.y * 64, j0 = blockIdx.x * 64;
  const int t = threadIdx.x, lane = t & 63, w = t >> 6;
  const int wr = w >> 1, wc = w & 1;
  const int lr = lane & 15, lk = lane >> 4;
  const int g8 = t & 7, rb = t >> 3;
  f32x4 acc[2][2] = {};
  for (int kk = 0; kk < C; kk += 64) {
    __syncthreads();
#pragma unroll
    for (int i = 0; i < 2; ++i) {
      int r = rb + i * 32;
      *(uint4*)&sAh[r * 64 + g8 * 8] = *(const uint4*)&Ah[(size_t)(i0 + r) * C + kk + g8 * 8];
      *(uint4*)&sAl[r * 64 + g8 * 8] = *(const uint4*)&Al[(size_t)(i0 + r) * C + kk + g8 * 8];
      *(uint4*)&sBh[r * 64 + g8 * 8] = *(const uint4*)&Bh[(size_t)(j0 + r) * C + kk + g8 * 8];
      *(uint4*)&sBl[r * 64 + g8 * 8] = *(const uint4*)&Bl[(size_t)(j0 + r) * C + kk + g8 * 8];
    }
    __syncthreads();
#pragma unroll
    for (int ks = 0; ks < 2; ++ks)
#pragma unroll
      for (int mi = 0; mi < 2; ++mi) {
        s16x8 ah = *(const s16x8*)&sAh[(wr * 32 + mi * 16 + lr) * 64 + ks * 32 + lk * 8];
        s16x8 al = *(const s16x8*)&sAl[(wr * 32 + mi * 16 + lr) * 64 + ks * 32 + lk * 8];
#pragma unroll
        for (int ni = 0; ni < 2; ++ni) {
          s16x8 bh = *(const s16x8*)&sBh[(wc * 32 + ni * 16 + lr) * 64 + ks * 32 + lk * 8];
          s16x8 bl = *(const s16x8*)&sBl[(wc * 32 + ni * 16 + lr) * 64 + ks * 32 + lk * 8];
          acc[mi][ni] = __builtin_amdgcn_mfma_f32_16x16x32_bf16(ah, bh, acc[mi][ni], 0, 0, 0);
          acc[mi][ni] = __builtin_amdgcn_mfma_f32_16x16x32_bf16(ah, bl, acc[mi][ni], 0, 0, 0);
          acc[mi][ni] = __builtin_amdgcn_mfma_f32_16x16x32_bf16(al, bh, acc[mi][ni], 0, 0, 0);
        }
      }
  }
#pragma unroll
  for (int mi = 0; mi < 2; ++mi)
#pragma unroll
    for (int ni = 0; ni < 2; ++ni)
#pragma unroll
      for (int j = 0; j < 4; ++j) {
        int rr = i0 + wr * 32 + mi * 16 + lk * 4 + j;
        int cc = j0 + wc * 32 + ni * 16 + lr;
        Mh[(size_t)rr * C + cc] = f2h(acc[mi][ni][j]);
      }
}

// --------------- 8-phase 256x256 fp16 GEMM, single-pass (K=C), R11 schedule
// MODE 0 (P):      P[nl][c'] = sum_c xh16[nl][c]*MTh[c'][c]; out fp16.
// MODE 1 (SCORES): S[l][m] = sum_c Ph[l][c]*xh16[m][c]; out bf16 e-values
//                  exp(S - blockmax) + block stats (bm, sum_e) per (col, by).
// Output store goes through an LDS repack (stride-264 u16 rows) so global
// writes are uint4 / 512B-per-wave segments. Copy loop: 128 rows x 32 quads
// = 4096 uint4 = 8 iterations x 512 threads (R15's k<16 overran LDS + E).
#define PH_OPEN() asm volatile("s_barrier" ::: "memory")
#define PH_CLOSE() asm volatile("s_barrier" ::: "memory")
#define VMCNT4() asm volatile("s_waitcnt vmcnt(4)" ::: "memory")
#define VMCNT0() asm volatile("s_waitcnt vmcnt(0)" ::: "memory")

#define MFMAQ(MH, NH, AV, BV)                                              \
  do {                                                                     \
    __builtin_amdgcn_s_setprio(1);                                         \
    _Pragma("unroll") for (int ks = 0; ks < 2; ++ks)                       \
        _Pragma("unroll") for (int mi = 0; mi < 4; ++mi)                   \
        _Pragma("unroll") for (int ni = 0; ni < 2; ++ni)                   \
            acc[MH * 4 + mi][NH * 2 + ni] =                                \
        __builtin_amdgcn_mfma_f32_16x16x32_f16(                            \
            AV[mi * 2 + ks], BV[ni * 2 + ks], acc[MH * 4 + mi][NH * 2 + ni], 0, 0, 0); \
    __builtin_amdgcn_s_setprio(0);                                         \
  } while (0)

template <int MODE>
__device__ __forceinline__ void gemm8_body(
    const u16* __restrict__ A0, const u16* __restrict__ B0,
    u16* __restrict__ Oh, u16* __restrict__ E,
    float2* __restrict__ PS, int n0) {
  constexpr int NT = 16;  // K-tiles of 64, K = C = 1024
  constexpr int NI = NT / 2;
  constexpr int SA = 2048, SB = 2048;
  constexpr int GXL = (MODE == 0) ? 2 : 3;
  constexpr int RPS = 264;  // repack stride (u16): 528B rows, uint4-aligned
  __shared__ u16 lds[65536];

  const int nwg = gridDim.x * gridDim.y * gridDim.z;
  int lin = ((int)blockIdx.z * gridDim.y + blockIdx.y) * gridDim.x + blockIdx.x;
  int swz = (lin & 7) * (nwg >> 3) + (lin >> 3);
  const int bx = swz & ((1 << GXL) - 1);
  int rem = swz >> GXL;
  const int by = (MODE == 0) ? rem : (rem & 7);
  const int bz = (MODE == 0) ? 0 : (rem >> 3);

  const int zn = bz;
  const int row0 = by * 256;
  const int col0 = bx * 256;
  const char *aB0, *bB0;
  if constexpr (MODE == 0) {
    aB0 = (const char*)(A0 + (size_t)row0 * C);   // xh16 rows
    bB0 = (const char*)(B0 + (size_t)col0 * C);   // MTh rows
  } else {
    const int n = n0 + zn;
    aB0 = (const char*)(A0 + ((size_t)n * L + row0) * C);  // Ph
    bB0 = (const char*)(B0 + ((size_t)n * L + col0) * C);  // xh16
  }

  const int t = threadIdx.x;
  const int lane = t & 63, w = t >> 6;
  const int wr = w >> 2, wc = w & 3;
  const int lr = lane & 15, lk = lane >> 4;

  const int rp0 = w * 8 + (lane >> 3);
  const int rp1 = 64 + rp0;
  const int g = (lane & 7) ^ ((lane >> 3) & 7);
  const int dO0 = w * 512 + (lane >> 3) * 64 + (lane & 7) * 8;
  const int dO1 = 4096 + dO0;
  const int sA0_0 = ((rp0 & 63) | ((rp0 >> 6) << 7)) * SA + g * 16;
  const int sA0_1 = ((rp1 & 63) | ((rp1 >> 6) << 7)) * SA + g * 16;
  const int sA1_0 = (((rp0 & 63) | 64) | ((rp0 >> 6) << 7)) * SA + g * 16;
  const int sA1_1 = (((rp1 & 63) | 64) | ((rp1 >> 6) << 7)) * SA + g * 16;
  const int sB0_0 = ((rp0 & 31) | ((rp0 >> 5) << 6)) * SB + g * 16;
  const int sB0_1 = ((rp1 & 31) | ((rp1 >> 5) << 6)) * SB + g * 16;
  const int sB1_0 = (((rp0 & 31) | 32) | ((rp0 >> 5) << 6)) * SB + g * 16;
  const int sB1_1 = (((rp1 & 31) | 32) | ((rp1 >> 5) << 6)) * SB + g * 16;

  auto stage = [&](int kt, int so0, int so1, int rbase, bool isB) {
    const char* p = isB ? bB0 : aB0;
    const int kOff = kt * 128;
    u16* dst = &lds[(kt & 1) * 32768 + rbase];
    gload16(p + kOff + so0, dst + dO0);
    gload16(p + kOff + so1, dst + dO1);
  };

  auto dsA = [&](int d, int mh, f16x8* av) {
#pragma unroll
    for (int mi = 0; mi < 4; ++mi)
#pragma unroll
      for (int ks = 0; ks < 2; ++ks)
        av[mi * 2 + ks] = *(const f16x8*)&lds[d * 32768 + mh * 8192 +
                                              (wr * 64 + mi * 16 + lr) * 64 +
                                              (((ks * 4 + lk) ^ (lr & 7)) * 8)];
  };
  auto dsB = [&](int d, int nh, f16x8* bv) {
#pragma unroll
    for (int ni = 0; ni < 2; ++ni)
#pragma unroll
      for (int ks = 0; ks < 2; ++ks)
        bv[ni * 2 + ks] = *(const f16x8*)&lds[d * 32768 + 16384 + nh * 8192 +
                                              (wc * 32 + ni * 16 + lr) * 64 +
                                              (((ks * 4 + lk) ^ (lr & 7)) * 8)];
  };

  f32x4 acc[8][4] = {};
  f16x8 av[8], b0v[4], b1v[4];

  // prologue: t0 fully + t1.{A0,B0}; b0v read AFTER the certifying barrier.
  stage(0, sA0_0, sA0_1, 0, false);
  stage(0, sB0_0, sB0_1, 16384, true);
  stage(0, sA1_0, sA1_1, 8192, false);
  stage(0, sB1_0, sB1_1, 24576, true);
  stage(1, sA0_0, sA0_1, 0, false);
  stage(1, sB0_0, sB0_1, 16384, true);
  VMCNT4();
  PH_CLOSE();
  dsB(0, 0, b0v);

  for (int i = 0; i < NI; ++i) {
    const int t1 = 2 * i + 1, t2 = 2 * i + 2, t3 = 2 * i + 3;
    dsA(0, 0, av);
    stage(t1, sA1_0, sA1_1, 8192, false);
    PH_OPEN();
    MFMAQ(0, 0, av, b0v);
    PH_CLOSE();
    dsB(0, 1, b1v);
    stage(t1, sB1_0, sB1_1, 24576, true);
    PH_OPEN();
    MFMAQ(0, 1, av, b1v);
    PH_CLOSE();
    dsA(0, 1, av);
    if (t2 < NT) stage(t2, sA0_0, sA0_1, 0, false);
    PH_OPEN();
    MFMAQ(1, 0, av, b0v);
    PH_CLOSE();
    if (t2 < NT) {
      stage(t2, sB0_0, sB0_1, 16384, true);
      VMCNT4();
    } else {
      VMCNT0();
    }
    PH_OPEN();
    dsB(1, 0, b0v);
    MFMAQ(1, 1, av, b1v);
    PH_CLOSE();
    dsA(1, 0, av);
    if (t2 < NT) stage(t2, sA1_0, sA1_1, 8192, false);
    PH_OPEN();
    MFMAQ(0, 0, av, b0v);
    PH_CLOSE();
    dsB(1, 1, b1v);
    if (t2 < NT) stage(t2, sB1_0, sB1_1, 24576, true);
    PH_OPEN();
    MFMAQ(0, 1, av, b1v);
    PH_CLOSE();
    dsA(1, 1, av);
    if (t3 < NT) stage(t3, sA0_0, sA0_1, 0, false);
    PH_OPEN();
    MFMAQ(1, 0, av, b0v);
    PH_CLOSE();
    if (t3 < NT) {
      stage(t3, sB0_0, sB0_1, 16384, true);
      VMCNT4();
    } else {
      VMCNT0();
    }
    PH_OPEN();
    dsB(0, 0, b0v);  // garbage on final iteration, unused
    MFMAQ(1, 1, av, b1v);
    PH_CLOSE();
  }
  asm volatile("s_waitcnt lgkmcnt(0)" ::: "memory");
  __syncthreads();

  // ------------------------------------------------------------ epilogue
  if constexpr (MODE == 0) {
    // fp16 store via LDS repack -> coalesced uint4 writes.
#pragma unroll
    for (int half = 0; half < 2; ++half) {
      if (wr == half) {
#pragma unroll
        for (int mg = 0; mg < 8; ++mg)
#pragma unroll
          for (int ng = 0; ng < 4; ++ng) {
            const int rl = (mg >> 2) * 64 + (mg & 3) * 16 + lk * 4;
            const int cl = wc * 64 + (ng >> 1) * 32 + (ng & 1) * 16 + lr;
#pragma unroll
            for (int j = 0; j < 4; ++j)
              lds[(rl + j) * RPS + cl] = f2h(acc[mg][ng][j]);
          }
      }
      __syncthreads();
#pragma unroll
      for (int k = 0; k < 8; ++k) {  // 128 rows x 32 quads = 4096 uint4
        const int lin2 = k * 512 + t;
        const int row = lin2 >> 5, gq = lin2 & 31;
        uint4 v = *(const uint4*)&lds[row * RPS + gq * 8];
        *(uint4*)&Oh[(size_t)(row0 + half * 128 + row) * C + col0 + gq * 8] = v;
      }
      __syncthreads();
    }
  } else {
    // e-value epilogue with repack: stats, then per-half exp->LDS->uint4.
    const int gn = n0 + zn;
    float* sm_ = (float*)&lds[33792];  // [256 cols][stride 9] maxes
    float* ss_ = sm_ + 2304;           // [256 cols][stride 9] sums
#pragma unroll
    for (int ng = 0; ng < 4; ++ng) {
      float mx = -3.0e38f;
#pragma unroll
      for (int mg = 0; mg < 8; ++mg)
#pragma unroll
        for (int j = 0; j < 4; ++j) mx = fmaxf(mx, acc[mg][ng][j]);
      const int cl = wc * 64 + (ng >> 1) * 32 + (ng & 1) * 16 + lr;
      sm_[cl * 9 + wr * 4 + lk] = mx;
    }
    __syncthreads();
    float bm[4];
#pragma unroll
    for (int ng = 0; ng < 4; ++ng) {
      const int cl = wc * 64 + (ng >> 1) * 32 + (ng & 1) * 16 + lr;
      float b = -3.0e38f;
#pragma unroll
      for (int s = 0; s < 8; ++s) b = fmaxf(b, sm_[cl * 9 + s]);
      bm[ng] = b;
    }
#pragma unroll
    for (int half = 0; half < 2; ++half) {
      if (wr == half) {
#pragma unroll
        for (int ng = 0; ng < 4; ++ng) {
          const int cl = wc * 64 + (ng >> 1) * 32 + (ng & 1) * 16 + lr;
          float sum = 0.f;
#pragma unroll
          for (int mg = 0; mg < 8; ++mg) {
            const int rl = (mg >> 2) * 64 + (mg & 3) * 16 + lk * 4;
#pragma unroll
            for (int j = 0; j < 4; ++j) {
              float ev = __expf(acc[mg][ng][j] - bm[ng]);
              sum += ev;
              lds[(rl + j) * RPS + cl] = f2bf(ev);
            }
          }
          ss_[cl * 9 + wr * 4 + lk] = sum;
        }
      }
      __syncthreads();
#pragma unroll
      for (int k = 0; k < 8; ++k) {  // 128 rows x 32 quads = 4096 uint4
        const int lin2 = k * 512 + t;
        const int row = lin2 >> 5, gq = lin2 & 31;
        uint4 v = *(const uint4*)&lds[row * RPS + gq * 8];
        *(uint4*)&E[((size_t)zn * L + row0 + half * 128 + row) * L + col0 + gq * 8] = v;
      }
      __syncthreads();
    }
    if (t < 256) {
      float b = -3.0e38f, sum = 0.f;
#pragma unroll
      for (int s = 0; s < 8; ++s) {
        b = fmaxf(b, sm_[t * 9 + s]);
        sum += ss_[t * 9 + s];
      }
      PS[((size_t)gn * L + col0 + t) * 8 + by] = make_float2(b, sum);
    }
  }
}

__global__ __launch_bounds__(512, 2) void g_p(
    const u16* A0, const u16* B0, u16* Oh) {
  gemm8_body<0>(A0, B0, Oh, nullptr, nullptr, 0);
}
__global__ __launch_bounds__(512, 2) void g_sc(
    const u16* A0, const u16* B0, u16* E, float2* PS, int n0) {
  gemm8_body<1>(A0, B0, nullptr, E, PS, n0);
}

// ---------------------- stats merge -> per-(segment, col) rescale factors
__global__ __launch_bounds__(256) void stats_merge(const float2* __restrict__ pstats,
                                                   float* __restrict__ fac,
                                                   int n0) {
  const int gn = n0 + blockIdx.z;
  const int m = blockIdx.x * 256 + threadIdx.x;
  const float2* p = &pstats[((size_t)gn * L + m) * 8];
  float2 pv[8];
  float gm = -3.0e38f;
#pragma unroll
  for (int j = 0; j < 8; ++j) { pv[j] = p[j]; gm = fmaxf(gm, pv[j].x); }
  float gs = 0.f;
#pragma unroll
  for (int j = 0; j < 8; ++j) gs += pv[j].y * __expf(pv[j].x - gm);
  const float inv = 1.f / gs;
#pragma unroll
  for (int s = 0; s < 8; ++s)
    fac[((size_t)gn * 8 + s) * L + m] = __expf(pv[s].x - gm) * inv;
}

// ------------------------------- out GEMM (bf16 e * fac staging, 128x256)
__global__ __launch_bounds__(512, 4) void gemm_out_k(
    const u16* __restrict__ e, const float* __restrict__ fac,
    const u16* __restrict__ xT, float* __restrict__ out, int n0) {
  __shared__ u16 lA[128 * 64];
  __shared__ u16 lB[256 * 64];
  const int nwg = gridDim.x * gridDim.y * gridDim.z;
  int lin = ((int)blockIdx.z * gridDim.y + blockIdx.y) * gridDim.x + blockIdx.x;
  int swz = (lin & 7) * (nwg >> 3) + (lin >> 3);
  const int bx = swz & 3, by = (swz >> 2) & 15, bz = swz >> 6;
  const int zn = bz, gn = n0 + zn;
  const int row0 = by * 128, col0 = bx * 256;
  const u16* Ee = e + (size_t)zn * L * L + (size_t)row0 * L;
  const float* fr = fac + ((size_t)gn * 8 + (by >> 1)) * L;
  const char* bB = (const char*)(xT + ((size_t)gn * C + col0) * L);
  float* O = out + ((size_t)gn * L + row0) * C + col0;

  const int t = threadIdx.x;
  const int lane = t & 63, w = t >> 6;
  const int wr = w >> 2, wc = w & 3;
  const int lr = lane & 15, lk = lane >> 4;
  const int c4 = t & 15, rb4 = t >> 4;
  const int gB = (t & 7) ^ ((t >> 3) & 7);
  const int Rb = t >> 3;

  auto aoff = [&](int r, int k) { return r * 64 + (((k >> 3) ^ (r & 7)) << 3) + (k & 7); };

  ushort4 ev4[4];
  float4 fv;
  auto loadA = [&](int kt) {
#pragma unroll
    for (int i = 0; i < 4; ++i)
      ev4[i] = *(const ushort4*)&Ee[(size_t)(rb4 + i * 32) * L + kt * 64 + c4 * 4];
    fv = *(const float4*)&fr[kt * 64 + c4 * 4];
  };

  f32x4 acc[4][4] = {};
  loadA(0);
  for (int kt = 0; kt < 32; ++kt) {
    ushort4 pk[4];
#pragma unroll
    for (int i = 0; i < 4; ++i) {
      pk[i].x = f2bf(bf2f(ev4[i].x) * fv.x);
      pk[i].y = f2bf(bf2f(ev4[i].y) * fv.y);
      pk[i].z = f2bf(bf2f(ev4[i].z) * fv.z);
      pk[i].w = f2bf(bf2f(ev4[i].w) * fv.w);
    }
    __syncthreads();
#pragma unroll
    for (int i = 0; i < 4; ++i)
      *(ushort4*)&lA[aoff(rb4 + i * 32, c4 * 4)] = pk[i];
#pragma unroll
    for (int i = 0; i < 4; ++i)
      gload16(bB + (size_t)(Rb + i * 64) * (L * 2) + kt * 128 + gB * 16,
              &lB[(Rb + i * 64) * 64 + (t & 7) * 8]);
    if (kt < 31) {
      loadA(kt + 1);  // 5 vmem after the 4 B-gloads
      asm volatile("s_waitcnt vmcnt(5) lgkmcnt(0)" ::: "memory");
    } else {
      asm volatile("s_waitcnt vmcnt(0) lgkmcnt(0)" ::: "memory");
    }
    __syncthreads();
#pragma unroll
    for (int ks = 0; ks < 2; ++ks) {
      s16x8 bf[4];
#pragma unroll
      for (int ni = 0; ni < 4; ++ni)
        bf[ni] = *(const s16x8*)&lB[aoff(wc * 64 + ni * 16 + lr, ks * 32 + lk * 8)];
      __builtin_amdgcn_s_setprio(1);
#pragma unroll
      for (int mi = 0; mi < 4; ++mi) {
        s16x8 af = *(const s16x8*)&lA[aoff(wr * 64 + mi * 16 + lr, ks * 32 + lk * 8)];
#pragma unroll
        for (int ni = 0; ni < 4; ++ni)
          acc[mi][ni] = __builtin_amdgcn_mfma_f32_16x16x32_bf16(af, bf[ni], acc[mi][ni], 0, 0, 0);
      }
      __builtin_amdgcn_s_setprio(0);
    }
  }
#pragma unroll
  for (int mi = 0; mi < 4; ++mi)
#pragma unroll
    for (int ni = 0; ni < 4; ++ni)
#pragma unroll
      for (int j = 0; j < 4; ++j)
        O[(size_t)(wr * 64 + mi * 16 + lk * 4 + j) * C + wc * 64 + ni * 16 + lr] =
            acc[mi][ni][j];
}

// ----------------------------------------------------------------- launch
extern "C" void kernel_launch(void* const* d_in, const int* in_sizes, int n_in,
                              void* d_out, int out_size, void* d_ws, size_t ws_size,
                              hipStream_t stream) {
  const float* x = (const float*)d_in[0];
  const float* Wq = (const float*)d_in[1];
  const float* Wk = (const float*)d_in[2];
  float* out = (float*)d_out;

  char* ws = (char*)d_ws;
  size_t off = 0;
  auto alloc = [&](size_t bytes) -> void* {
    void* p = ws + off;
    off = (off + bytes + 255) & ~(size_t)255;
    return p;
  };
  u16* MTh = (u16*)alloc((size_t)C * C * 2);
  u16* WqTh = (u16*)alloc((size_t)C * C * 2);
  u16* WqTl = (u16*)alloc((size_t)C * C * 2);
  u16* WkTh = (u16*)alloc((size_t)C * C * 2);
  u16* WkTl = (u16*)alloc((size_t)C * C * 2);
  u16* xh = (u16*)alloc((size_t)NL * C * 2);     // fp16 x
  u16* xT = (u16*)alloc((size_t)N * C * L * 2);  // bf16 x^T
  u16* Ph = (u16*)alloc((size_t)NL * C * 2);     // fp16 P
  float2* pstats = (float2*)alloc((size_t)N * L * 8 * 8);
  float* fac = (float*)alloc((size_t)N * 8 * L * 4);
  const size_t base = off;
  const size_t per_n = (size_t)L * L * 2;  // bf16 e-values
  size_t avail = ws_size > base ? ws_size - base : 0;
  int chunk = (int)(avail / per_n);
  if (chunk < 1) chunk = 1;
  if (chunk > 16) chunk = 16;
  u16* e = (u16*)(ws + base);

  xprep<<<dim3(L / 64, C / 64, N), dim3(256), 0, stream>>>(x, xh, xT);
  transpose_w<<<dim3(16, 16, 2), dim3(256), 0, stream>>>(Wq, Wk, WqTh, WqTl, WkTh, WkTl);
  g_m<<<dim3(16, 16), dim3(256), 0, stream>>>(WqTh, WqTl, WkTh, WkTl, MTh);
  g_p<<<dim3(4, 128), dim3(512), 0, stream>>>(xh, MTh, Ph);
  for (int n0 = 0; n0 < N; n0 += chunk) {
    int cn = (N - n0) < chunk ? (N - n0) : chunk;
    g_sc<<<dim3(8, 8, cn), dim3(512), 0, stream>>>(Ph, xh, e, pstats, n0);
    stats_merge<<<dim3(L / 256, 1, cn), dim3(256), 0, stream>>>(pstats, fac, n0);
    gemm_out_k<<<dim3(4, 16, cn), dim3(512), 0, stream>>>(e, fac, xT, out, n0);
  }
}

// Round 17
// 499.748 us; speedup vs baseline: 2.0921x; 1.0296x over previous
//
#include <hip/hip_runtime.h>

typedef unsigned short u16;
typedef __attribute__((ext_vector_type(4))) float f32x4;
typedef __attribute__((ext_vector_type(8))) short s16x8;
typedef _Float16 f16x8 __attribute__((ext_vector_type(8)));
typedef _Float16 f16x4 __attribute__((ext_vector_type(4)));

constexpr int N = 16, L = 2048, C = 1024;
constexpr int NL = N * L;

__device__ __forceinline__ u16 f2bf(float v) {
  unsigned u = __float_as_uint(v);
  return (u16)((u + 0x7FFFu + ((u >> 16) & 1u)) >> 16);
}
__device__ __forceinline__ u16 f2h(float v) {
  _Float16 h = (_Float16)v;
  return __builtin_bit_cast(u16, h);
}
__device__ __forceinline__ float bf2f(u16 h) { return __uint_as_float(((unsigned)h) << 16); }

__device__ __forceinline__ void gload16(const void* g, const void* l) {
  __builtin_amdgcn_global_load_lds((const __attribute__((address_space(1))) void*)g,
                                   (__attribute__((address_space(3))) void*)l, 16, 0, 0);
}

// ------------------------------------------------- fused x preprocessing
// x [N][L][C] fp32 -> xh16 (fp16, same layout) + xT [N][C][L] fp16
__global__ __launch_bounds__(256) void xprep(const float* __restrict__ x,
                                             u16* __restrict__ xh,
                                             u16* __restrict__ xT) {
  __shared__ u16 tile[64 * 68];
  const int n = blockIdx.z;
  const int l0 = blockIdx.x * 64;
  const int c0 = blockIdx.y * 64;
  const int t = threadIdx.x;
  const int cg = t & 15, r = t >> 4;
#pragma unroll
  for (int i = 0; i < 4; ++i) {
    int rr = r + i * 16;
    size_t idx = ((size_t)n * L + l0 + rr) * C + c0 + cg * 4;
    float4 v = *(const float4*)&x[idx];
    ushort4 h;
    h.x = f2h(v.x); h.y = f2h(v.y); h.z = f2h(v.z); h.w = f2h(v.w);
    *(ushort4*)&xh[idx] = h;
    *(ushort4*)&tile[rr * 68 + cg * 4] = h;
  }
  __syncthreads();
  const int l4 = (t & 15) * 4;
#pragma unroll
  for (int i = 0; i < 4; ++i) {
    int cc = (t >> 4) + i * 16;
    ushort4 o;
    o.x = tile[(l4 + 0) * 68 + cc];
    o.y = tile[(l4 + 1) * 68 + cc];
    o.z = tile[(l4 + 2) * 68 + cc];
    o.w = tile[(l4 + 3) * 68 + cc];
    *(ushort4*)&xT[((size_t)n * C + c0 + cc) * L + l0 + l4] = o;
  }
}

// --------------------------------------- W transpose + bf16 hi/lo split
__global__ __launch_bounds__(256) void transpose_w(
    const float* __restrict__ Wq, const float* __restrict__ Wk,
    u16* __restrict__ WqTh, u16* __restrict__ WqTl,
    u16* __restrict__ WkTh, u16* __restrict__ WkTl) {
  __shared__ u16 th[64 * 68], tl[64 * 68];
  const float* W = blockIdx.z ? Wk : Wq;
  u16* Th = blockIdx.z ? WkTh : WqTh;
  u16* Tl = blockIdx.z ? WkTl : WqTl;
  const int a0 = blockIdx.x * 64, c0 = blockIdx.y * 64;
  const int t = threadIdx.x, cg = t & 15, r = t >> 4;
#pragma unroll
  for (int i = 0; i < 4; ++i) {
    int rr = r + i * 16;
    float4 v = *(const float4*)&W[(size_t)(a0 + rr) * C + c0 + cg * 4];
    ushort4 h, l;
    h.x = f2bf(v.x); l.x = f2bf(v.x - bf2f(h.x));
    h.y = f2bf(v.y); l.y = f2bf(v.y - bf2f(h.y));
    h.z = f2bf(v.z); l.z = f2bf(v.z - bf2f(h.z));
    h.w = f2bf(v.w); l.w = f2bf(v.w - bf2f(h.w));
    *(ushort4*)&th[rr * 68 + cg * 4] = h;
    *(ushort4*)&tl[rr * 68 + cg * 4] = l;
  }
  __syncthreads();
  const int a4 = (t & 15) * 4;
#pragma unroll
  for (int i = 0; i < 4; ++i) {
    int cc = (t >> 4) + i * 16;
    ushort4 oh, ol;
    oh.x = th[(a4 + 0) * 68 + cc]; ol.x = tl[(a4 + 0) * 68 + cc];
    oh.y = th[(a4 + 1) * 68 + cc]; ol.y = tl[(a4 + 1) * 68 + cc];
    oh.z = th[(a4 + 2) * 68 + cc]; ol.z = tl[(a4 + 2) * 68 + cc];
    oh.w = th[(a4 + 3) * 68 + cc]; ol.w = tl[(a4 + 3) * 68 + cc];
    *(ushort4*)&Th[(size_t)(c0 + cc) * C + a0 + a4] = oh;
    *(ushort4*)&Tl[(size_t)(c0 + cc) * C + a0 + a4] = ol;
  }
}

// ------------------- MT = Wq^T * Wk (bf16 3-pass, tiny) -> fp16 out
__global__ __launch_bounds__(256) void g_m(
    const u16* __restrict__ Ah, const u16* __restrict__ Al,
    const u16* __restrict__ Bh, const u16* __restrict__ Bl,
    u16* __restrict__ Mh) {
  __shared__ u16 sAh[64 * 64], sAl[64 * 64], sBh[64 * 64], sBl[64 * 64];
  const int i0 = blockIdx.y * 64, j0 = blockIdx.x * 64;
  const int t = threadIdx.x, lane = t & 63, w = t >> 6;
  const int wr = w >> 1, wc = w & 1;
  const int lr = lane & 15, lk = lane >> 4;
  const int g8 = t & 7, rb = t >> 3;
  f32x4 acc[2][2] = {};
  for (int kk = 0; kk < C; kk += 64) {
    __syncthreads();
#pragma unroll
    for (int i = 0; i < 2; ++i) {
      int r = rb + i * 32;
      *(uint4*)&sAh[r * 64 + g8 * 8] = *(const uint4*)&Ah[(size_t)(i0 + r) * C + kk + g8 * 8];
      *(uint4*)&sAl[r * 64 + g8 * 8] = *(const uint4*)&Al[(size_t)(i0 + r) * C + kk + g8 * 8];
      *(uint4*)&sBh[r * 64 + g8 * 8] = *(const uint4*)&Bh[(size_t)(j0 + r) * C + kk + g8 * 8];
      *(uint4*)&sBl[r * 64 + g8 * 8] = *(const uint4*)&Bl[(size_t)(j0 + r) * C + kk + g8 * 8];
    }
    __syncthreads();
#pragma unroll
    for (int ks = 0; ks < 2; ++ks)
#pragma unroll
      for (int mi = 0; mi < 2; ++mi) {
        s16x8 ah = *(const s16x8*)&sAh[(wr * 32 + mi * 16 + lr) * 64 + ks * 32 + lk * 8];
        s16x8 al = *(const s16x8*)&sAl[(wr * 32 + mi * 16 + lr) * 64 + ks * 32 + lk * 8];
#pragma unroll
        for (int ni = 0; ni < 2; ++ni) {
          s16x8 bh = *(const s16x8*)&sBh[(wc * 32 + ni * 16 + lr) * 64 + ks * 32 + lk * 8];
          s16x8 bl = *(const s16x8*)&sBl[(wc * 32 + ni * 16 + lr) * 64 + ks * 32 + lk * 8];
          acc[mi][ni] = __builtin_amdgcn_mfma_f32_16x16x32_bf16(ah, bh, acc[mi][ni], 0, 0, 0);
          acc[mi][ni] = __builtin_amdgcn_mfma_f32_16x16x32_bf16(ah, bl, acc[mi][ni], 0, 0, 0);
          acc[mi][ni] = __builtin_amdgcn_mfma_f32_16x16x32_bf16(al, bh, acc[mi][ni], 0, 0, 0);
        }
      }
  }
#pragma unroll
  for (int mi = 0; mi < 2; ++mi)
#pragma unroll
    for (int ni = 0; ni < 2; ++ni)
#pragma unroll
      for (int j = 0; j < 4; ++j) {
        int rr = i0 + wr * 32 + mi * 16 + lk * 4 + j;
        int cc = j0 + wc * 32 + ni * 16 + lr;
        Mh[(size_t)rr * C + cc] = f2h(acc[mi][ni][j]);
      }
}

// --------------- 8-phase 256x256 fp16 GEMM, single-pass (K=C), R11 schedule
// MODE 0 (P):      P[nl][c'] = sum_c xh16[nl][c]*MTh[c'][c]; out fp16.
// MODE 1 (SCORES): S[l][m] = sum_c Ph[l][c]*xh16[m][c]; out fp16 e-values
//                  exp(S - blockmax) + block stats (bm, sum_e) per (col, by).
// Output store goes through an LDS repack (stride-264 u16 rows) so global
// writes are uint4 / 512B-per-wave segments.
#define PH_OPEN() asm volatile("s_barrier" ::: "memory")
#define PH_CLOSE() asm volatile("s_barrier" ::: "memory")
#define VMCNT4() asm volatile("s_waitcnt vmcnt(4)" ::: "memory")
#define VMCNT0() asm volatile("s_waitcnt vmcnt(0)" ::: "memory")

#define MFMAQ(MH, NH, AV, BV)                                              \
  do {                                                                     \
    __builtin_amdgcn_s_setprio(1);                                         \
    _Pragma("unroll") for (int ks = 0; ks < 2; ++ks)                       \
        _Pragma("unroll") for (int mi = 0; mi < 4; ++mi)                   \
        _Pragma("unroll") for (int ni = 0; ni < 2; ++ni)                   \
            acc[MH * 4 + mi][NH * 2 + ni] =                                \
        __builtin_amdgcn_mfma_f32_16x16x32_f16(                            \
            AV[mi * 2 + ks], BV[ni * 2 + ks], acc[MH * 4 + mi][NH * 2 + ni], 0, 0, 0); \
    __builtin_amdgcn_s_setprio(0);                                         \
  } while (0)

template <int MODE>
__device__ __forceinline__ void gemm8_body(
    const u16* __restrict__ A0, const u16* __restrict__ B0,
    u16* __restrict__ Oh, u16* __restrict__ E,
    float2* __restrict__ PS, int n0) {
  constexpr int NT = 16;  // K-tiles of 64, K = C = 1024
  constexpr int NI = NT / 2;
  constexpr int SA = 2048, SB = 2048;
  constexpr int GXL = (MODE == 0) ? 2 : 3;
  constexpr int RPS = 264;  // repack stride (u16): 528B rows, uint4-aligned
  __shared__ u16 lds[65536];

  const int nwg = gridDim.x * gridDim.y * gridDim.z;
  int lin = ((int)blockIdx.z * gridDim.y + blockIdx.y) * gridDim.x + blockIdx.x;
  int swz = (lin & 7) * (nwg >> 3) + (lin >> 3);
  const int bx = swz & ((1 << GXL) - 1);
  int rem = swz >> GXL;
  const int by = (MODE == 0) ? rem : (rem & 7);
  const int bz = (MODE == 0) ? 0 : (rem >> 3);

  const int zn = bz;
  const int row0 = by * 256;
  const int col0 = bx * 256;
  const char *aB0, *bB0;
  if constexpr (MODE == 0) {
    aB0 = (const char*)(A0 + (size_t)row0 * C);   // xh16 rows
    bB0 = (const char*)(B0 + (size_t)col0 * C);   // MTh rows
  } else {
    const int n = n0 + zn;
    aB0 = (const char*)(A0 + ((size_t)n * L + row0) * C);  // Ph
    bB0 = (const char*)(B0 + ((size_t)n * L + col0) * C);  // xh16
  }

  const int t = threadIdx.x;
  const int lane = t & 63, w = t >> 6;
  const int wr = w >> 2, wc = w & 3;
  const int lr = lane & 15, lk = lane >> 4;

  const int rp0 = w * 8 + (lane >> 3);
  const int rp1 = 64 + rp0;
  const int g = (lane & 7) ^ ((lane >> 3) & 7);
  const int dO0 = w * 512 + (lane >> 3) * 64 + (lane & 7) * 8;
  const int dO1 = 4096 + dO0;
  const int sA0_0 = ((rp0 & 63) | ((rp0 >> 6) << 7)) * SA + g * 16;
  const int sA0_1 = ((rp1 & 63) | ((rp1 >> 6) << 7)) * SA + g * 16;
  const int sA1_0 = (((rp0 & 63) | 64) | ((rp0 >> 6) << 7)) * SA + g * 16;
  const int sA1_1 = (((rp1 & 63) | 64) | ((rp1 >> 6) << 7)) * SA + g * 16;
  const int sB0_0 = ((rp0 & 31) | ((rp0 >> 5) << 6)) * SB + g * 16;
  const int sB0_1 = ((rp1 & 31) | ((rp1 >> 5) << 6)) * SB + g * 16;
  const int sB1_0 = (((rp0 & 31) | 32) | ((rp0 >> 5) << 6)) * SB + g * 16;
  const int sB1_1 = (((rp1 & 31) | 32) | ((rp1 >> 5) << 6)) * SB + g * 16;

  auto stage = [&](int kt, int so0, int so1, int rbase, bool isB) {
    const char* p = isB ? bB0 : aB0;
    const int kOff = kt * 128;
    u16* dst = &lds[(kt & 1) * 32768 + rbase];
    gload16(p + kOff + so0, dst + dO0);
    gload16(p + kOff + so1, dst + dO1);
  };

  auto dsA = [&](int d, int mh, f16x8* av) {
#pragma unroll
    for (int mi = 0; mi < 4; ++mi)
#pragma unroll
      for (int ks = 0; ks < 2; ++ks)
        av[mi * 2 + ks] = *(const f16x8*)&lds[d * 32768 + mh * 8192 +
                                              (wr * 64 + mi * 16 + lr) * 64 +
                                              (((ks * 4 + lk) ^ (lr & 7)) * 8)];
  };
  auto dsB = [&](int d, int nh, f16x8* bv) {
#pragma unroll
    for (int ni = 0; ni < 2; ++ni)
#pragma unroll
      for (int ks = 0; ks < 2; ++ks)
        bv[ni * 2 + ks] = *(const f16x8*)&lds[d * 32768 + 16384 + nh * 8192 +
                                              (wc * 32 + ni * 16 + lr) * 64 +
                                              (((ks * 4 + lk) ^ (lr & 7)) * 8)];
  };

  f32x4 acc[8][4] = {};
  f16x8 av[8], b0v[4], b1v[4];

  // prologue: t0 fully + t1.{A0,B0}; b0v read AFTER the certifying barrier.
  stage(0, sA0_0, sA0_1, 0, false);
  stage(0, sB0_0, sB0_1, 16384, true);
  stage(0, sA1_0, sA1_1, 8192, false);
  stage(0, sB1_0, sB1_1, 24576, true);
  stage(1, sA0_0, sA0_1, 0, false);
  stage(1, sB0_0, sB0_1, 16384, true);
  VMCNT4();
  PH_CLOSE();
  dsB(0, 0, b0v);

  for (int i = 0; i < NI; ++i) {
    const int t1 = 2 * i + 1, t2 = 2 * i + 2, t3 = 2 * i + 3;
    dsA(0, 0, av);
    stage(t1, sA1_0, sA1_1, 8192, false);
    PH_OPEN();
    MFMAQ(0, 0, av, b0v);
    PH_CLOSE();
    dsB(0, 1, b1v);
    stage(t1, sB1_0, sB1_1, 24576, true);
    PH_OPEN();
    MFMAQ(0, 1, av, b1v);
    PH_CLOSE();
    dsA(0, 1, av);
    if (t2 < NT) stage(t2, sA0_0, sA0_1, 0, false);
    PH_OPEN();
    MFMAQ(1, 0, av, b0v);
    PH_CLOSE();
    if (t2 < NT) {
      stage(t2, sB0_0, sB0_1, 16384, true);
      VMCNT4();
    } else {
      VMCNT0();
    }
    PH_OPEN();
    dsB(1, 0, b0v);
    MFMAQ(1, 1, av, b1v);
    PH_CLOSE();
    dsA(1, 0, av);
    if (t2 < NT) stage(t2, sA1_0, sA1_1, 8192, false);
    PH_OPEN();
    MFMAQ(0, 0, av, b0v);
    PH_CLOSE();
    dsB(1, 1, b1v);
    if (t2 < NT) stage(t2, sB1_0, sB1_1, 24576, true);
    PH_OPEN();
    MFMAQ(0, 1, av, b1v);
    PH_CLOSE();
    dsA(1, 1, av);
    if (t3 < NT) stage(t3, sA0_0, sA0_1, 0, false);
    PH_OPEN();
    MFMAQ(1, 0, av, b0v);
    PH_CLOSE();
    if (t3 < NT) {
      stage(t3, sB0_0, sB0_1, 16384, true);
      VMCNT4();
    } else {
      VMCNT0();
    }
    PH_OPEN();
    dsB(0, 0, b0v);  // garbage on final iteration, unused
    MFMAQ(1, 1, av, b1v);
    PH_CLOSE();
  }
  asm volatile("s_waitcnt lgkmcnt(0)" ::: "memory");
  __syncthreads();

  // ------------------------------------------------------------ epilogue
  if constexpr (MODE == 0) {
    // fp16 store via LDS repack -> coalesced uint4 writes.
#pragma unroll
    for (int half = 0; half < 2; ++half) {
      if (wr == half) {
#pragma unroll
        for (int mg = 0; mg < 8; ++mg)
#pragma unroll
          for (int ng = 0; ng < 4; ++ng) {
            const int rl = (mg >> 2) * 64 + (mg & 3) * 16 + lk * 4;
            const int cl = wc * 64 + (ng >> 1) * 32 + (ng & 1) * 16 + lr;
#pragma unroll
            for (int j = 0; j < 4; ++j)
              lds[(rl + j) * RPS + cl] = f2h(acc[mg][ng][j]);
          }
      }
      __syncthreads();
#pragma unroll
      for (int k = 0; k < 8; ++k) {  // 128 rows x 32 quads = 4096 uint4
        const int lin2 = k * 512 + t;
        const int row = lin2 >> 5, gq = lin2 & 31;
        uint4 v = *(const uint4*)&lds[row * RPS + gq * 8];
        *(uint4*)&Oh[(size_t)(row0 + half * 128 + row) * C + col0 + gq * 8] = v;
      }
      __syncthreads();
    }
  } else {
    // e-value epilogue with repack: stats, then per-half exp->LDS->uint4.
    const int gn = n0 + zn;
    float* sm_ = (float*)&lds[33792];  // [256 cols][stride 9] maxes
    float* ss_ = sm_ + 2304;           // [256 cols][stride 9] sums
#pragma unroll
    for (int ng = 0; ng < 4; ++ng) {
      float mx = -3.0e38f;
#pragma unroll
      for (int mg = 0; mg < 8; ++mg)
#pragma unroll
        for (int j = 0; j < 4; ++j) mx = fmaxf(mx, acc[mg][ng][j]);
      const int cl = wc * 64 + (ng >> 1) * 32 + (ng & 1) * 16 + lr;
      sm_[cl * 9 + wr * 4 + lk] = mx;
    }
    __syncthreads();
    float bm[4];
#pragma unroll
    for (int ng = 0; ng < 4; ++ng) {
      const int cl = wc * 64 + (ng >> 1) * 32 + (ng & 1) * 16 + lr;
      float b = -3.0e38f;
#pragma unroll
      for (int s = 0; s < 8; ++s) b = fmaxf(b, sm_[cl * 9 + s]);
      bm[ng] = b;
    }
#pragma unroll
    for (int half = 0; half < 2; ++half) {
      if (wr == half) {
#pragma unroll
        for (int ng = 0; ng < 4; ++ng) {
          const int cl = wc * 64 + (ng >> 1) * 32 + (ng & 1) * 16 + lr;
          float sum = 0.f;
#pragma unroll
          for (int mg = 0; mg < 8; ++mg) {
            const int rl = (mg >> 2) * 64 + (mg & 3) * 16 + lk * 4;
#pragma unroll
            for (int j = 0; j < 4; ++j) {
              float ev = __expf(acc[mg][ng][j] - bm[ng]);
              sum += ev;
              lds[(rl + j) * RPS + cl] = f2h(ev);
            }
          }
          ss_[cl * 9 + wr * 4 + lk] = sum;
        }
      }
      __syncthreads();
#pragma unroll
      for (int k = 0; k < 8; ++k) {  // 128 rows x 32 quads = 4096 uint4
        const int lin2 = k * 512 + t;
        const int row = lin2 >> 5, gq = lin2 & 31;
        uint4 v = *(const uint4*)&lds[row * RPS + gq * 8];
        *(uint4*)&E[((size_t)zn * L + row0 + half * 128 + row) * L + col0 + gq * 8] = v;
      }
      __syncthreads();
    }
    if (t < 256) {
      float b = -3.0e38f, sum = 0.f;
#pragma unroll
      for (int s = 0; s < 8; ++s) {
        b = fmaxf(b, sm_[t * 9 + s]);
        sum += ss_[t * 9 + s];
      }
      PS[((size_t)gn * L + col0 + t) * 8 + by] = make_float2(b, sum);
    }
  }
}

__global__ __launch_bounds__(512, 2) void g_p(
    const u16* A0, const u16* B0, u16* Oh) {
  gemm8_body<0>(A0, B0, Oh, nullptr, nullptr, 0);
}
__global__ __launch_bounds__(512, 2) void g_sc(
    const u16* A0, const u16* B0, u16* E, float2* PS, int n0) {
  gemm8_body<1>(A0, B0, nullptr, E, PS, n0);
}

// ---------------------- stats merge -> per-(segment, col) fp16 factors
__global__ __launch_bounds__(256) void stats_merge(const float2* __restrict__ pstats,
                                                   u16* __restrict__ fac,
                                                   int n0) {
  const int gn = n0 + blockIdx.z;
  const int m = blockIdx.x * 256 + threadIdx.x;
  const float2* p = &pstats[((size_t)gn * L + m) * 8];
  float2 pv[8];
  float gm = -3.0e38f;
#pragma unroll
  for (int j = 0; j < 8; ++j) { pv[j] = p[j]; gm = fmaxf(gm, pv[j].x); }
  float gs = 0.f;
#pragma unroll
  for (int j = 0; j < 8; ++j) gs += pv[j].y * __expf(pv[j].x - gm);
  const float inv = 1.f / gs;
#pragma unroll
  for (int s = 0; s < 8; ++s)
    fac[((size_t)gn * 8 + s) * L + m] = f2h(__expf(pv[s].x - gm) * inv);
}

// ------------------------------- out GEMM (fp16 e * fac, pk-mul, 128x256)
__global__ __launch_bounds__(512, 4) void gemm_out_k(
    const u16* __restrict__ e, const u16* __restrict__ fac,
    const u16* __restrict__ xT, float* __restrict__ out, int n0) {
  __shared__ u16 lA[128 * 64];
  __shared__ u16 lB[256 * 64];
  const int nwg = gridDim.x * gridDim.y * gridDim.z;
  int lin = ((int)blockIdx.z * gridDim.y + blockIdx.y) * gridDim.x + blockIdx.x;
  int swz = (lin & 7) * (nwg >> 3) + (lin >> 3);
  const int bx = swz & 3, by = (swz >> 2) & 15, bz = swz >> 6;
  const int zn = bz, gn = n0 + zn;
  const int row0 = by * 128, col0 = bx * 256;
  const u16* Ee = e + (size_t)zn * L * L + (size_t)row0 * L;
  const u16* fr16 = fac + ((size_t)gn * 8 + (by >> 1)) * L;
  const char* bB = (const char*)(xT + ((size_t)gn * C + col0) * L);
  float* O = out + ((size_t)gn * L + row0) * C + col0;

  const int t = threadIdx.x;
  const int lane = t & 63, w = t >> 6;
  const int wr = w >> 2, wc = w & 3;
  const int lr = lane & 15, lk = lane >> 4;
  const int c4 = t & 15, rb4 = t >> 4;
  const int gB = (t & 7) ^ ((t >> 3) & 7);
  const int Rb = t >> 3;

  auto aoff = [&](int r, int k) { return r * 64 + (((k >> 3) ^ (r & 7)) << 3) + (k & 7); };

  f16x4 ev4[4];
  f16x4 fv16;
  auto loadA = [&](int kt) {
#pragma unroll
    for (int i = 0; i < 4; ++i)
      ev4[i] = *(const f16x4*)&Ee[(size_t)(rb4 + i * 32) * L + kt * 64 + c4 * 4];
    fv16 = *(const f16x4*)&fr16[kt * 64 + c4 * 4];
  };

  f32x4 acc[4][4] = {};
  loadA(0);
  for (int kt = 0; kt < 32; ++kt) {
    f16x4 pk[4];
#pragma unroll
    for (int i = 0; i < 4; ++i) pk[i] = ev4[i] * fv16;  // v_pk_mul_f16
    __syncthreads();
#pragma unroll
    for (int i = 0; i < 4; ++i)
      *(f16x4*)&lA[aoff(rb4 + i * 32, c4 * 4)] = pk[i];
#pragma unroll
    for (int i = 0; i < 4; ++i)
      gload16(bB + (size_t)(Rb + i * 64) * (L * 2) + kt * 128 + gB * 16,
              &lB[(Rb + i * 64) * 64 + (t & 7) * 8]);
    if (kt < 31) {
      loadA(kt + 1);  // 5 vmem after the 4 B-gloads
      asm volatile("s_waitcnt vmcnt(5) lgkmcnt(0)" ::: "memory");
    } else {
      asm volatile("s_waitcnt vmcnt(0) lgkmcnt(0)" ::: "memory");
    }
    __syncthreads();
#pragma unroll
    for (int ks = 0; ks < 2; ++ks) {
      f16x8 bf[4];
#pragma unroll
      for (int ni = 0; ni < 4; ++ni)
        bf[ni] = *(const f16x8*)&lB[aoff(wc * 64 + ni * 16 + lr, ks * 32 + lk * 8)];
      __builtin_amdgcn_s_setprio(1);
#pragma unroll
      for (int mi = 0; mi < 4; ++mi) {
        f16x8 af = *(const f16x8*)&lA[aoff(wr * 64 + mi * 16 + lr, ks * 32 + lk * 8)];
#pragma unroll
        for (int ni = 0; ni < 4; ++ni)
          acc[mi][ni] = __builtin_amdgcn_mfma_f32_16x16x32_f16(af, bf[ni], acc[mi][ni], 0, 0, 0);
      }
      __builtin_amdgcn_s_setprio(0);
    }
  }
#pragma unroll
  for (int mi = 0; mi < 4; ++mi)
#pragma unroll
    for (int ni = 0; ni < 4; ++ni)
#pragma unroll
      for (int j = 0; j < 4; ++j)
        O[(size_t)(wr * 64 + mi * 16 + lk * 4 + j) * C + wc * 64 + ni * 16 + lr] =
            acc[mi][ni][j];
}

// ----------------------------------------------------------------- launch
extern "C" void kernel_launch(void* const* d_in, const int* in_sizes, int n_in,
                              void* d_out, int out_size, void* d_ws, size_t ws_size,
                              hipStream_t stream) {
  const float* x = (const float*)d_in[0];
  const float* Wq = (const float*)d_in[1];
  const float* Wk = (const float*)d_in[2];
  float* out = (float*)d_out;

  char* ws = (char*)d_ws;
  size_t off = 0;
  auto alloc = [&](size_t bytes) -> void* {
    void* p = ws + off;
    off = (off + bytes + 255) & ~(size_t)255;
    return p;
  };
  u16* MTh = (u16*)alloc((size_t)C * C * 2);
  u16* WqTh = (u16*)alloc((size_t)C * C * 2);
  u16* WqTl = (u16*)alloc((size_t)C * C * 2);
  u16* WkTh = (u16*)alloc((size_t)C * C * 2);
  u16* WkTl = (u16*)alloc((size_t)C * C * 2);
  u16* xh = (u16*)alloc((size_t)NL * C * 2);     // fp16 x
  u16* xT = (u16*)alloc((size_t)N * C * L * 2);  // fp16 x^T
  u16* Ph = (u16*)alloc((size_t)NL * C * 2);     // fp16 P
  float2* pstats = (float2*)alloc((size_t)N * L * 8 * 8);
  u16* fac = (u16*)alloc((size_t)N * 8 * L * 2); // fp16 factors
  const size_t base = off;
  const size_t per_n = (size_t)L * L * 2;  // fp16 e-values
  size_t avail = ws_size > base ? ws_size - base : 0;
  int chunk = (int)(avail / per_n);
  if (chunk < 1) chunk = 1;
  if (chunk > 16) chunk = 16;
  u16* e = (u16*)(ws + base);

  xprep<<<dim3(L / 64, C / 64, N), dim3(256), 0, stream>>>(x, xh, xT);
  transpose_w<<<dim3(16, 16, 2), dim3(256), 0, stream>>>(Wq, Wk, WqTh, WqTl, WkTh, WkTl);
  g_m<<<dim3(16, 16), dim3(256), 0, stream>>>(WqTh, WqTl, WkTh, WkTl, MTh);
  g_p<<<dim3(4, 128), dim3(512), 0, stream>>>(xh, MTh, Ph);
  for (int n0 = 0; n0 < N; n0 += chunk) {
    int cn = (N - n0) < chunk ? (N - n0) : chunk;
    g_sc<<<dim3(8, 8, cn), dim3(512), 0, stream>>>(Ph, xh, e, pstats, n0);
    stats_merge<<<dim3(L / 256, 1, cn), dim3(256), 0, stream>>>(pstats, fac, n0);
    gemm_out_k<<<dim3(4, 16, cn), dim3(512), 0, stream>>>(e, fac, xT, out, n0);
  }
}